// Round 1
// baseline (710.176 us; speedup 1.0000x reference)
//
#include <hip/hip_runtime.h>
#include <math.h>

// Problem constants
constexpr int SEQ   = 512;
constexpr int HDIM  = 64;
constexpr int NHEAD = 12;
constexpr int NBATCH = 2;
constexpr int CDIM  = 768;
constexpr int TOPM  = 16;
constexpr int SMAX  = 8;
constexpr float NEGINF = -1e30f;

// ---------------------------------------------------------------
// Kernel 1: QKV = x @ w_qkv + b_qkv, scattered to q/k/v [24,512,64]
// M=1024, N=2304, K=768. 64x64 tiles, 256 threads, 4x4 micro-tile.
// ---------------------------------------------------------------
__global__ __launch_bounds__(256) void qkv_gemm_kernel(
    const float* __restrict__ x, const float* __restrict__ w,
    const float* __restrict__ bias,
    float* __restrict__ q, float* __restrict__ k, float* __restrict__ v)
{
    __shared__ float As[16][65];
    __shared__ float Bs[16][65];
    const int bm = blockIdx.y * 64;
    const int bn = blockIdx.x * 64;
    const int tid = threadIdx.x;
    const int tm = (tid >> 4) << 2;
    const int tn = (tid & 15) << 2;
    float acc[4][4] = {};
    for (int k0 = 0; k0 < CDIM; k0 += 16) {
        #pragma unroll
        for (int l = 0; l < 4; ++l) {
            int idx = tid + l * 256;
            int m = idx >> 4, kk = idx & 15;
            As[kk][m] = x[(bm + m) * CDIM + k0 + kk];
        }
        #pragma unroll
        for (int l = 0; l < 4; ++l) {
            int idx = tid + l * 256;
            int kk = idx >> 6, nn = idx & 63;
            Bs[kk][nn] = w[(k0 + kk) * (3 * CDIM) + bn + nn];
        }
        __syncthreads();
        #pragma unroll
        for (int kk = 0; kk < 16; ++kk) {
            float a[4], b[4];
            #pragma unroll
            for (int u = 0; u < 4; ++u) a[u] = As[kk][tm + u];
            #pragma unroll
            for (int u = 0; u < 4; ++u) b[u] = Bs[kk][tn + u];
            #pragma unroll
            for (int u = 0; u < 4; ++u)
                #pragma unroll
                for (int w2 = 0; w2 < 4; ++w2)
                    acc[u][w2] = fmaf(a[u], b[w2], acc[u][w2]);
        }
        __syncthreads();
    }
    #pragma unroll
    for (int u = 0; u < 4; ++u) {
        int m = bm + tm + u;
        int b_ = m >> 9, t = m & 511;
        #pragma unroll
        for (int w2 = 0; w2 < 4; ++w2) {
            int cc = bn + tn + w2;
            float val = acc[u][w2] + bias[cc];
            int part = cc / CDIM;
            int c2 = cc - part * CDIM;
            int h = c2 >> 6, d = c2 & 63;
            float* dst = (part == 0) ? q : ((part == 1) ? k : v);
            dst[(((b_ * NHEAD + h) * SEQ) + t) * HDIM + d] = val;
        }
    }
}

// ---------------------------------------------------------------
// Kernel 2: fused standard-causal-attention + DPP greedy attention
// One block (256 threads) per (head n, token i). Shares the k_j.q_i
// dot products between the two paths.
// ---------------------------------------------------------------
__global__ __launch_bounds__(256) void attn_dpp_kernel(
    const float* __restrict__ q, const float* __restrict__ k,
    const float* __restrict__ v, const float* __restrict__ gate_p,
    float* __restrict__ y)
{
    const int i = blockIdx.x;
    const int n = blockIdx.y;
    const int tid = threadIdx.x;
    const float* kh = k + (size_t)n * SEQ * HDIM;
    const float* vh = v + (size_t)n * SEQ * HDIM;
    const float* qi = q + ((size_t)n * SEQ + i) * HDIM;

    __shared__ float sim[SEQ];
    __shared__ float prob[SEQ];
    __shared__ double gram[17][17];
    __shared__ int topidx[TOPM];
    __shared__ int Eidx[17];
    __shared__ int selIdx[SMAX];
    __shared__ int selN_s;
    __shared__ float qv[HDIM];
    __shared__ float red[256];
    __shared__ float wdpp[SMAX];
    __shared__ float ystd_part[4][HDIM];
    __shared__ float ystd_s[HDIM];

    if (tid < HDIM) qv[tid] = qi[tid];
    __syncthreads();

    // ---- similarity row: sim[j] = k_j . q_i for j<=i, else -1e30 ----
    for (int j = tid; j < SEQ; j += 256) {
        float s;
        if (j <= i) {
            const float4* kr = (const float4*)(kh + j * HDIM);
            float acc = 0.f;
            #pragma unroll
            for (int d4 = 0; d4 < 16; ++d4) {
                float4 kk4 = kr[d4];
                acc = fmaf(kk4.x, qv[d4 * 4 + 0], acc);
                acc = fmaf(kk4.y, qv[d4 * 4 + 1], acc);
                acc = fmaf(kk4.z, qv[d4 * 4 + 2], acc);
                acc = fmaf(kk4.w, qv[d4 * 4 + 3], acc);
            }
            s = acc;
        } else {
            s = NEGINF;
        }
        sim[j] = s;
    }
    __syncthreads();

    // ---- top-16 (wave 0 only; stable ties = lowest index, matching lax.top_k) ----
    if (tid < 64) {
        float vals[8]; int idxs[8];
        #pragma unroll
        for (int m = 0; m < 8; ++m) { int j = tid + (m << 6); vals[m] = sim[j]; idxs[m] = j; }
        for (int s = 0; s < TOPM; ++s) {
            float bv = vals[0]; int bi = idxs[0];
            #pragma unroll
            for (int m = 1; m < 8; ++m)
                if (vals[m] > bv) { bv = vals[m]; bi = idxs[m]; }  // within lane, idx ascending: strict > keeps lowest
            float rv = bv; int ri = bi;
            #pragma unroll
            for (int off = 32; off; off >>= 1) {
                float ov = __shfl_xor(rv, off);
                int oi = __shfl_xor(ri, off);
                if (ov > rv || (ov == rv && oi < ri)) { rv = ov; ri = oi; }
            }
            if (tid == 0) topidx[s] = ri;
            if ((ri & 63) == tid) {
                int om = ri >> 6;
                #pragma unroll
                for (int m = 0; m < 8; ++m) if (m == om) vals[m] = -2e30f;
            }
        }
    }
    __syncthreads();

    if (tid == 0) Eidx[0] = i;
    if (tid < TOPM) Eidx[1 + tid] = topidx[tid];
    __syncthreads();

    // ---- 17x17 Gram of {i} U top-16 candidate keys, double precision ----
    for (int e = tid; e < 289; e += 256) {
        int a = e / 17, bcol = e % 17;
        const float* ka = kh + Eidx[a] * HDIM;
        const float* kb = kh + Eidx[bcol] * HDIM;
        double acc = 0.0;
        #pragma unroll
        for (int d = 0; d < HDIM; ++d) acc += (double)ka[d] * (double)kb[d];
        gram[a][bcol] = acc;
    }
    __syncthreads();

    // ---- greedy DPP selection via incremental Cholesky (wave 0, lanes=candidates) ----
    if (tid < 64) {
        const int c = tid;
        const bool isCand = (c < TOPM);
        const int nvalid = (i + 1 < TOPM) ? (i + 1) : TOPM;
        bool active = isCand && (c < nvalid) && (Eidx[1 + c] != i);
        double zc[7];
        #pragma unroll
        for (int t = 0; t < 7; ++t) zc[t] = 0.0;
        double det = gram[0][0];
        double cur = log(det + 1e-6);
        double cnorm = isCand ? gram[1 + c][1 + c] : 0.0;
        double L00 = sqrt(det > 0.0 ? det : 1e-30);
        if (isCand) zc[0] = gram[1 + c][0] / L00;
        int selI[SMAX];
        #pragma unroll
        for (int t = 0; t < SMAX; ++t) selI[t] = i;
        int sc = 1;

        for (int it = 0; it < SMAX - 1; ++it) {
            double dc = cnorm;
            #pragma unroll
            for (int t = 0; t < 7; ++t) if (t < sc) dc -= zc[t] * zc[t];
            double detn = det * dc;
            double arg = detn + 1e-6;
            // arg<=0: ref's fp32 log gives NaN which wins jnp.argmax; mimic with +huge
            double score = (arg > 0.0) ? log(arg) / (double)(sc + 1) : 1e31;
            double msc = active ? score : -1e30;
            double rv2 = msc; int rc = c;
            #pragma unroll
            for (int off = 32; off; off >>= 1) {
                double ov = __shfl_xor(rv2, off);
                int oc = __shfl_xor(rc, off);
                if (ov > rv2 || (ov == rv2 && oc < rc)) { rv2 = ov; rc = oc; }
            }
            bool any = (__any(active ? 1 : 0) != 0);
            bool take = any && ((rv2 > cur) || (sc < 4));
            if (!take) break;

            double dbest = __shfl(dc, rc);
            double Lss = sqrt(dbest > 1e-30 ? dbest : 1e-30);
            double zb[7];
            #pragma unroll
            for (int t = 0; t < 7; ++t) zb[t] = __shfl(zc[t], rc);
            if (isCand) {
                double crossn = gram[1 + c][1 + rc];
                double s2 = 0.0;
                #pragma unroll
                for (int t = 0; t < 7; ++t) if (t < sc) s2 += zc[t] * zb[t];
                double znew = (crossn - s2) / Lss;
                #pragma unroll
                for (int t = 0; t < 7; ++t) if (t == sc) zc[t] = znew;
            }
            det = det * dbest;
            cur = rv2;
            if (c == rc) active = false;
            int newIdx = Eidx[1 + rc];
            #pragma unroll
            for (int t = 0; t < SMAX; ++t) if (t == sc) selI[t] = newIdx;
            ++sc;
        }
        if (tid == 0) {
            selN_s = sc;
            #pragma unroll
            for (int s = 0; s < SMAX; ++s) if (s < sc) selIdx[s] = selI[s];
        }
    }
    __syncthreads();

    // ---- standard causal softmax attention ----
    const float scale = 0.125f;  // 1/sqrt(64)
    float lm = -1e30f;
    for (int j = tid; j < SEQ; j += 256) {
        float a = (j <= i) ? sim[j] * scale : NEGINF;
        prob[j] = a;
        lm = fmaxf(lm, a);
    }
    red[tid] = lm;
    __syncthreads();
    #pragma unroll
    for (int off = 128; off; off >>= 1) {
        if (tid < off) red[tid] = fmaxf(red[tid], red[tid + off]);
        __syncthreads();
    }
    float mx = red[0];
    __syncthreads();
    float ls = 0.f;
    for (int j = tid; j < SEQ; j += 256) {
        float p = expf(prob[j] - mx);
        prob[j] = p;
        ls += p;
    }
    red[tid] = ls;
    __syncthreads();
    #pragma unroll
    for (int off = 128; off; off >>= 1) {
        if (tid < off) red[tid] += red[tid + off];
        __syncthreads();
    }
    float denom = red[0];
    __syncthreads();

    {
        int d = tid & 63, g = tid >> 6;
        float acc2 = 0.f;
        for (int j = g; j <= i; j += 4) acc2 = fmaf(prob[j], vh[j * HDIM + d], acc2);
        ystd_part[g][d] = acc2;
    }
    __syncthreads();
    if (tid < HDIM)
        ystd_s[tid] = (ystd_part[0][tid] + ystd_part[1][tid] +
                       ystd_part[2][tid] + ystd_part[3][tid]) / denom;

    // ---- DPP attention over selected subset ----
    if (tid == 0) {
        int sn = selN_s;
        float mmx = -1e30f;
        #pragma unroll
        for (int s = 0; s < SMAX; ++s) if (s < sn) mmx = fmaxf(mmx, sim[selIdx[s]] * scale);
        float ssum = 0.f;
        float wl[SMAX];
        #pragma unroll
        for (int s = 0; s < SMAX; ++s) {
            if (s < sn) { wl[s] = expf(sim[selIdx[s]] * scale - mmx); ssum += wl[s]; }
        }
        #pragma unroll
        for (int s = 0; s < SMAX; ++s) if (s < sn) wdpp[s] = wl[s] / ssum;
    }
    __syncthreads();

    float gp = gate_p[0];
    float gate = 1.f / (1.f + expf(-gp));
    if (tid < HDIM) {
        float yd = 0.f;
        int sn = selN_s;
        #pragma unroll
        for (int s = 0; s < SMAX; ++s)
            if (s < sn) yd = fmaf(wdpp[s], vh[selIdx[s] * HDIM + tid], yd);
        y[((size_t)n * SEQ + i) * HDIM + tid] = gate * yd + (1.f - gate) * ystd_s[tid];
    }
}

// ---------------------------------------------------------------
// Kernel 3: out = reshape(y) @ w_proj + b_proj
// A is gathered from head layout [24,512,64] -> [1024,768].
// ---------------------------------------------------------------
__global__ __launch_bounds__(256) void proj_gemm_kernel(
    const float* __restrict__ y, const float* __restrict__ w,
    const float* __restrict__ bias, float* __restrict__ out)
{
    __shared__ float As[16][65];
    __shared__ float Bs[16][65];
    const int bm = blockIdx.y * 64;
    const int bn = blockIdx.x * 64;
    const int tid = threadIdx.x;
    const int tm = (tid >> 4) << 2;
    const int tn = (tid & 15) << 2;
    float acc[4][4] = {};
    for (int k0 = 0; k0 < CDIM; k0 += 16) {
        #pragma unroll
        for (int l = 0; l < 4; ++l) {
            int idx = tid + l * 256;
            int m = idx >> 4, kk = idx & 15;
            int row = bm + m;
            int col = k0 + kk;
            int b_ = row >> 9, t = row & 511;
            int h = col >> 6, d = col & 63;
            As[kk][m] = y[(((b_ * NHEAD + h) * SEQ) + t) * HDIM + d];
        }
        #pragma unroll
        for (int l = 0; l < 4; ++l) {
            int idx = tid + l * 256;
            int kk = idx >> 6, nn = idx & 63;
            Bs[kk][nn] = w[(k0 + kk) * CDIM + bn + nn];
        }
        __syncthreads();
        #pragma unroll
        for (int kk = 0; kk < 16; ++kk) {
            float a[4], b[4];
            #pragma unroll
            for (int u = 0; u < 4; ++u) a[u] = As[kk][tm + u];
            #pragma unroll
            for (int u = 0; u < 4; ++u) b[u] = Bs[kk][tn + u];
            #pragma unroll
            for (int u = 0; u < 4; ++u)
                #pragma unroll
                for (int w2 = 0; w2 < 4; ++w2)
                    acc[u][w2] = fmaf(a[u], b[w2], acc[u][w2]);
        }
        __syncthreads();
    }
    #pragma unroll
    for (int u = 0; u < 4; ++u) {
        int m = bm + tm + u;
        #pragma unroll
        for (int w2 = 0; w2 < 4; ++w2) {
            int cc = bn + tn + w2;
            out[m * CDIM + cc] = acc[u][w2] + bias[cc];
        }
    }
}

extern "C" void kernel_launch(void* const* d_in, const int* in_sizes, int n_in,
                              void* d_out, int out_size, void* d_ws, size_t ws_size,
                              hipStream_t stream)
{
    const float* x      = (const float*)d_in[0];
    const float* w_qkv  = (const float*)d_in[1];
    const float* b_qkv  = (const float*)d_in[2];
    const float* w_proj = (const float*)d_in[3];
    const float* b_proj = (const float*)d_in[4];
    const float* gate_p = (const float*)d_in[5];
    float* out = (float*)d_out;

    float* ws = (float*)d_ws;
    const size_t HS = (size_t)NBATCH * NHEAD * SEQ * HDIM;  // 786432
    float* q = ws;
    float* k = q + HS;
    float* v = k + HS;
    float* y = v + HS;

    qkv_gemm_kernel<<<dim3((3 * CDIM) / 64, (NBATCH * SEQ) / 64), 256, 0, stream>>>(
        x, w_qkv, b_qkv, q, k, v);
    attn_dpp_kernel<<<dim3(SEQ, NBATCH * NHEAD), 256, 0, stream>>>(
        q, k, v, gate_p, y);
    proj_gemm_kernel<<<dim3(CDIM / 64, (NBATCH * SEQ) / 64), 256, 0, stream>>>(
        y, w_proj, b_proj, out);
}

// Round 2
// 464.100 us; speedup vs baseline: 1.5302x; 1.5302x over previous
//
#include <hip/hip_runtime.h>
#include <math.h>

// Problem constants
constexpr int SEQ   = 512;
constexpr int HDIM  = 64;
constexpr int NHEAD = 12;
constexpr int NBATCH = 2;
constexpr int CDIM  = 768;
constexpr int TOPM  = 16;
constexpr int SMAX  = 8;
constexpr float NEGINF = -1e30f;

// ---------------------------------------------------------------
// Kernel 1: QKV = x @ w_qkv + b_qkv, scattered to q/k/v [24,512,64]
// ---------------------------------------------------------------
__global__ __launch_bounds__(256) void qkv_gemm_kernel(
    const float* __restrict__ x, const float* __restrict__ w,
    const float* __restrict__ bias,
    float* __restrict__ q, float* __restrict__ k, float* __restrict__ v)
{
    __shared__ float As[16][65];
    __shared__ float Bs[16][65];
    const int bm = blockIdx.y * 64;
    const int bn = blockIdx.x * 64;
    const int tid = threadIdx.x;
    const int tm = (tid >> 4) << 2;
    const int tn = (tid & 15) << 2;
    float acc[4][4] = {};
    for (int k0 = 0; k0 < CDIM; k0 += 16) {
        #pragma unroll
        for (int l = 0; l < 4; ++l) {
            int idx = tid + l * 256;
            int m = idx >> 4, kk = idx & 15;
            As[kk][m] = x[(bm + m) * CDIM + k0 + kk];
        }
        #pragma unroll
        for (int l = 0; l < 4; ++l) {
            int idx = tid + l * 256;
            int kk = idx >> 6, nn = idx & 63;
            Bs[kk][nn] = w[(k0 + kk) * (3 * CDIM) + bn + nn];
        }
        __syncthreads();
        #pragma unroll
        for (int kk = 0; kk < 16; ++kk) {
            float a[4], b[4];
            #pragma unroll
            for (int u = 0; u < 4; ++u) a[u] = As[kk][tm + u];
            #pragma unroll
            for (int u = 0; u < 4; ++u) b[u] = Bs[kk][tn + u];
            #pragma unroll
            for (int u = 0; u < 4; ++u)
                #pragma unroll
                for (int w2 = 0; w2 < 4; ++w2)
                    acc[u][w2] = fmaf(a[u], b[w2], acc[u][w2]);
        }
        __syncthreads();
    }
    #pragma unroll
    for (int u = 0; u < 4; ++u) {
        int m = bm + tm + u;
        int b_ = m >> 9, t = m & 511;
        #pragma unroll
        for (int w2 = 0; w2 < 4; ++w2) {
            int cc = bn + tn + w2;
            float val = acc[u][w2] + bias[cc];
            int part = cc / CDIM;
            int c2 = cc - part * CDIM;
            int h = c2 >> 6, d = c2 & 63;
            float* dst = (part == 0) ? q : ((part == 1) ? k : v);
            dst[(((b_ * NHEAD + h) * SEQ) + t) * HDIM + d] = val;
        }
    }
}

// ---------------------------------------------------------------
// Kernel 2: fused standard + DPP attention. ONE WAVE PER TOKEN,
// 4 tokens per 256-thread block. All phases wave-parallel; only 3
// cross-wave barriers (LDS safety fences between phases).
// ---------------------------------------------------------------
__global__ __launch_bounds__(256) void attn_dpp_kernel(
    const float* __restrict__ q, const float* __restrict__ k,
    const float* __restrict__ v, const float* __restrict__ gate_p,
    float* __restrict__ y)
{
    const int tid  = threadIdx.x;
    const int wid  = tid >> 6;
    const int lane = tid & 63;
    const int i = blockIdx.x * 4 + wid;
    const int n = blockIdx.y;
    const float* kh = k + (size_t)n * SEQ * HDIM;
    const float* vh = v + (size_t)n * SEQ * HDIM;
    const float* qi = q + ((size_t)n * SEQ + i) * HDIM;

    __shared__ float  prob[4][SEQ];       // 8 KB  : unnormalized softmax numerators
    __shared__ double gram[4][17][17];    // 9.25KB: fp64 Gram of {i} U top-16
    __shared__ float  qsh[4][HDIM];       // 1 KB
    __shared__ int    eidx[4][17];        // 272 B

    qsh[wid][lane] = qi[lane];
    __syncthreads();

    // ---- phase 1: sim row (registers), top-16, softmax numerators ----
    float sim8[8];   // raw k_j . q_i (masked to NEGINF for j>i)
    #pragma unroll
    for (int m = 0; m < 8; ++m) {
        int j = lane + (m << 6);
        float acc = NEGINF;
        if (j <= i) {
            const float4* kr = (const float4*)(kh + j * HDIM);
            float a = 0.f;
            #pragma unroll
            for (int d4 = 0; d4 < 16; ++d4) {
                float4 kk4 = kr[d4];
                a = fmaf(kk4.x, qsh[wid][d4 * 4 + 0], a);
                a = fmaf(kk4.y, qsh[wid][d4 * 4 + 1], a);
                a = fmaf(kk4.z, qsh[wid][d4 * 4 + 2], a);
                a = fmaf(kk4.w, qsh[wid][d4 * 4 + 3], a);
            }
            acc = a;
        }
        sim8[m] = acc;
    }

    // top-16 (stable ties = lowest index, matching lax.top_k)
    {
        float vals[8];
        #pragma unroll
        for (int m = 0; m < 8; ++m) vals[m] = sim8[m];
        if (lane == 0) eidx[wid][0] = i;
        #pragma unroll
        for (int s = 0; s < TOPM; ++s) {
            float bv = vals[0]; int bi = lane;
            #pragma unroll
            for (int m = 1; m < 8; ++m)
                if (vals[m] > bv) { bv = vals[m]; bi = lane + (m << 6); }
            float rv = bv; int ri = bi;
            #pragma unroll
            for (int off = 32; off; off >>= 1) {
                float ov = __shfl_xor(rv, off);
                int   oi = __shfl_xor(ri, off);
                if (ov > rv || (ov == rv && oi < ri)) { rv = ov; ri = oi; }
            }
            if (lane == 0) eidx[wid][1 + s] = ri;
            if ((ri & 63) == lane) {
                int om = ri >> 6;
                #pragma unroll
                for (int m = 0; m < 8; ++m) if (m == om) vals[m] = -2e30f;
            }
        }
    }

    // softmax stats from registers (scale = 1/sqrt(64))
    const float scale = 0.125f;
    float lm = -3e38f;
    #pragma unroll
    for (int m = 0; m < 8; ++m) lm = fmaxf(lm, sim8[m]);
    #pragma unroll
    for (int off = 32; off; off >>= 1) lm = fmaxf(lm, __shfl_xor(lm, off));
    const float mx = lm * scale;
    float sum = 0.f;
    #pragma unroll
    for (int m = 0; m < 8; ++m) {
        float p = expf(sim8[m] * scale - mx);   // 0 for masked entries
        prob[wid][lane + (m << 6)] = p;
        sum += p;
    }
    #pragma unroll
    for (int off = 32; off; off >>= 1) sum += __shfl_xor(sum, off);
    const float denom = sum;
    __syncthreads();

    // ---- phase 2: 17x17 fp64 Gram via triangular symmetry (153 dots) ----
    for (int e = lane; e < 153; e += 64) {
        int a = 0, start = 0;
        while (start + a + 1 <= e) { start += a + 1; ++a; }
        int b = e - start;
        const float4* ka4 = (const float4*)(kh + eidx[wid][a] * HDIM);
        const float4* kb4 = (const float4*)(kh + eidx[wid][b] * HDIM);
        double s = 0.0;
        #pragma unroll
        for (int d4 = 0; d4 < 16; ++d4) {
            float4 av = ka4[d4], bv = kb4[d4];
            s += (double)av.x * bv.x + (double)av.y * bv.y
               + (double)av.z * bv.z + (double)av.w * bv.w;
        }
        gram[wid][a][b] = s;
        gram[wid][b][a] = s;
    }
    __syncthreads();

    // ---- phase 3: greedy DPP selection via incremental Cholesky ----
    // (all 64 lanes run it; lanes 0..15 are candidates, rest inert)
    int   selI[SMAX];
    int   sc = 1;
    {
        const int c = lane;
        const bool isCand = (c < TOPM);
        const int nvalid = (i + 1 < TOPM) ? (i + 1) : TOPM;
        bool active = isCand && (c < nvalid) && (eidx[wid][1 + c] != i);
        double zc[7];
        #pragma unroll
        for (int t = 0; t < 7; ++t) zc[t] = 0.0;
        double det = gram[wid][0][0];
        double cur = log(det + 1e-6);
        double cnorm = isCand ? gram[wid][1 + c][1 + c] : 0.0;
        double L00 = sqrt(det > 0.0 ? det : 1e-30);
        if (isCand) zc[0] = gram[wid][1 + c][0] / L00;
        #pragma unroll
        for (int t = 0; t < SMAX; ++t) selI[t] = i;

        for (int it = 0; it < SMAX - 1; ++it) {
            double dc = cnorm;
            #pragma unroll
            for (int t = 0; t < 7; ++t) if (t < sc) dc -= zc[t] * zc[t];
            double detn = det * dc;
            double arg = detn + 1e-6;
            // arg<=0: ref's fp32 log -> NaN wins jnp.argmax; mimic with +huge
            double score = (arg > 0.0) ? log(arg) / (double)(sc + 1) : 1e31;
            double rv2 = active ? score : -1e30;
            int rc = c;
            #pragma unroll
            for (int off = 32; off; off >>= 1) {
                double ov = __shfl_xor(rv2, off);
                int    oc = __shfl_xor(rc, off);
                if (ov > rv2 || (ov == rv2 && oc < rc)) { rv2 = ov; rc = oc; }
            }
            bool any = (__any(active ? 1 : 0) != 0);
            bool take = any && ((rv2 > cur) || (sc < 4));
            if (!take) break;

            double dbest = __shfl(dc, rc);
            double Lss = sqrt(dbest > 1e-30 ? dbest : 1e-30);
            double zb[7];
            #pragma unroll
            for (int t = 0; t < 7; ++t) zb[t] = __shfl(zc[t], rc);
            if (isCand) {
                double crossn = gram[wid][1 + c][1 + rc];
                double s2 = 0.0;
                #pragma unroll
                for (int t = 0; t < 7; ++t) if (t < sc) s2 += zc[t] * zb[t];
                double znew = (crossn - s2) / Lss;
                #pragma unroll
                for (int t = 0; t < 7; ++t) if (t == sc) zc[t] = znew;
            }
            det = det * dbest;
            cur = rv2;
            if (c == rc) active = false;
            int newIdx = eidx[wid][1 + rc];
            #pragma unroll
            for (int t = 0; t < SMAX; ++t) if (t == sc) selI[t] = newIdx;
            ++sc;
        }
    }

    // ---- phase 4: PV (standard), DPP combine, output. lane = d. ----
    float accv = 0.f;
    {
        const int d = lane;
        int j = 0;
        for (; j + 4 <= i + 1; j += 4) {
            float p0 = prob[wid][j + 0];
            float p1 = prob[wid][j + 1];
            float p2 = prob[wid][j + 2];
            float p3 = prob[wid][j + 3];
            accv = fmaf(p0, vh[(j + 0) * HDIM + d], accv);
            accv = fmaf(p1, vh[(j + 1) * HDIM + d], accv);
            accv = fmaf(p2, vh[(j + 2) * HDIM + d], accv);
            accv = fmaf(p3, vh[(j + 3) * HDIM + d], accv);
        }
        for (; j <= i; ++j) accv = fmaf(prob[wid][j], vh[j * HDIM + d], accv);
    }
    const float ystd = accv / denom;

    // DPP weights: softmax over selected logits == p[sel] / sum(p[sel])
    float wsum = 0.f;
    #pragma unroll
    for (int s = 0; s < SMAX; ++s) if (s < sc) wsum += prob[wid][selI[s]];
    float yd = 0.f;
    #pragma unroll
    for (int s = 0; s < SMAX; ++s)
        if (s < sc) yd = fmaf(prob[wid][selI[s]], vh[selI[s] * HDIM + lane], yd);
    yd /= wsum;

    const float gp = gate_p[0];
    const float gate = 1.f / (1.f + expf(-gp));
    y[((size_t)n * SEQ + i) * HDIM + lane] = gate * yd + (1.f - gate) * ystd;
}

// ---------------------------------------------------------------
// Kernel 3: out = reshape(y) @ w_proj + b_proj
// ---------------------------------------------------------------
__global__ __launch_bounds__(256) void proj_gemm_kernel(
    const float* __restrict__ y, const float* __restrict__ w,
    const float* __restrict__ bias, float* __restrict__ out)
{
    __shared__ float As[16][65];
    __shared__ float Bs[16][65];
    const int bm = blockIdx.y * 64;
    const int bn = blockIdx.x * 64;
    const int tid = threadIdx.x;
    const int tm = (tid >> 4) << 2;
    const int tn = (tid & 15) << 2;
    float acc[4][4] = {};
    for (int k0 = 0; k0 < CDIM; k0 += 16) {
        #pragma unroll
        for (int l = 0; l < 4; ++l) {
            int idx = tid + l * 256;
            int m = idx >> 4, kk = idx & 15;
            int row = bm + m;
            int col = k0 + kk;
            int b_ = row >> 9, t = row & 511;
            int h = col >> 6, d = col & 63;
            As[kk][m] = y[(((b_ * NHEAD + h) * SEQ) + t) * HDIM + d];
        }
        #pragma unroll
        for (int l = 0; l < 4; ++l) {
            int idx = tid + l * 256;
            int kk = idx >> 6, nn = idx & 63;
            Bs[kk][nn] = w[(k0 + kk) * CDIM + bn + nn];
        }
        __syncthreads();
        #pragma unroll
        for (int kk = 0; kk < 16; ++kk) {
            float a[4], b[4];
            #pragma unroll
            for (int u = 0; u < 4; ++u) a[u] = As[kk][tm + u];
            #pragma unroll
            for (int u = 0; u < 4; ++u) b[u] = Bs[kk][tn + u];
            #pragma unroll
            for (int u = 0; u < 4; ++u)
                #pragma unroll
                for (int w2 = 0; w2 < 4; ++w2)
                    acc[u][w2] = fmaf(a[u], b[w2], acc[u][w2]);
        }
        __syncthreads();
    }
    #pragma unroll
    for (int u = 0; u < 4; ++u) {
        int m = bm + tm + u;
        #pragma unroll
        for (int w2 = 0; w2 < 4; ++w2) {
            int cc = bn + tn + w2;
            out[m * CDIM + cc] = acc[u][w2] + bias[cc];
        }
    }
}

extern "C" void kernel_launch(void* const* d_in, const int* in_sizes, int n_in,
                              void* d_out, int out_size, void* d_ws, size_t ws_size,
                              hipStream_t stream)
{
    const float* x      = (const float*)d_in[0];
    const float* w_qkv  = (const float*)d_in[1];
    const float* b_qkv  = (const float*)d_in[2];
    const float* w_proj = (const float*)d_in[3];
    const float* b_proj = (const float*)d_in[4];
    const float* gate_p = (const float*)d_in[5];
    float* out = (float*)d_out;

    float* ws = (float*)d_ws;
    const size_t HS = (size_t)NBATCH * NHEAD * SEQ * HDIM;  // 786432
    float* q = ws;
    float* k = q + HS;
    float* v = k + HS;
    float* y = v + HS;

    qkv_gemm_kernel<<<dim3((3 * CDIM) / 64, (NBATCH * SEQ) / 64), 256, 0, stream>>>(
        x, w_qkv, b_qkv, q, k, v);
    attn_dpp_kernel<<<dim3(SEQ / 4, NBATCH * NHEAD), 256, 0, stream>>>(
        q, k, v, gate_p, y);
    proj_gemm_kernel<<<dim3(CDIM / 64, (NBATCH * SEQ) / 64), 256, 0, stream>>>(
        y, w_proj, b_proj, out);
}

// Round 3
// 345.340 us; speedup vs baseline: 2.0565x; 1.3439x over previous
//
#include <hip/hip_runtime.h>
#include <math.h>

// Problem constants
constexpr int SEQ   = 512;
constexpr int HDIM  = 64;
constexpr int NHEAD = 12;
constexpr int NBATCH = 2;
constexpr int CDIM  = 768;
constexpr int TOPM  = 16;
constexpr int SMAX  = 8;
constexpr float NEGINF = -1e30f;

// ---------------------------------------------------------------
// Kernel 1: QKV = x @ w_qkv + b_qkv, scattered to q/k/v [24,512,64]
// 64x64 tile, BK=16, float4 staging, ds_read_b128 fragments.
// ---------------------------------------------------------------
__global__ __launch_bounds__(256) void qkv_gemm_kernel(
    const float* __restrict__ x, const float* __restrict__ w,
    const float* __restrict__ bias,
    float* __restrict__ q, float* __restrict__ k, float* __restrict__ v)
{
    __shared__ float As[16][68];
    __shared__ float Bs[16][68];
    const int bm = blockIdx.y * 64;
    const int bn = blockIdx.x * 64;
    const int tid = threadIdx.x;
    const int tm = (tid >> 4) << 2;
    const int tn = (tid & 15) << 2;
    const int lm = tid >> 2;          // staging: row of A
    const int lkq = (tid & 3) << 2;   //          k-quad of A
    const int lkk = tid >> 4;         // staging: k of B
    const int lnq = (tid & 15) << 2;  //          n-quad of B
    float acc[4][4] = {};
    for (int k0 = 0; k0 < CDIM; k0 += 16) {
        float4 av = *(const float4*)(x + (bm + lm) * CDIM + k0 + lkq);
        float4 bv = *(const float4*)(w + (k0 + lkk) * (3 * CDIM) + bn + lnq);
        As[lkq + 0][lm] = av.x;
        As[lkq + 1][lm] = av.y;
        As[lkq + 2][lm] = av.z;
        As[lkq + 3][lm] = av.w;
        *(float4*)&Bs[lkk][lnq] = bv;
        __syncthreads();
        #pragma unroll
        for (int kk = 0; kk < 16; ++kk) {
            float4 a4 = *(const float4*)&As[kk][tm];
            float4 b4 = *(const float4*)&Bs[kk][tn];
            float a[4] = {a4.x, a4.y, a4.z, a4.w};
            float b[4] = {b4.x, b4.y, b4.z, b4.w};
            #pragma unroll
            for (int u = 0; u < 4; ++u)
                #pragma unroll
                for (int w2 = 0; w2 < 4; ++w2)
                    acc[u][w2] = fmaf(a[u], b[w2], acc[u][w2]);
        }
        __syncthreads();
    }
    #pragma unroll
    for (int u = 0; u < 4; ++u) {
        int m = bm + tm + u;
        int b_ = m >> 9, t = m & 511;
        #pragma unroll
        for (int w2 = 0; w2 < 4; ++w2) {
            int cc = bn + tn + w2;
            float val = acc[u][w2] + bias[cc];
            int part = cc / CDIM;
            int c2 = cc - part * CDIM;
            int h = c2 >> 6, d = c2 & 63;
            float* dst = (part == 0) ? q : ((part == 1) ? k : v);
            dst[(((b_ * NHEAD + h) * SEQ) + t) * HDIM + d] = val;
        }
    }
}

// ---------------------------------------------------------------
// Kernel 2: fused standard + DPP attention. ONE WAVE PER BLOCK,
// processing the balanced token pair {z, 511-z}. All phases
// wave-parallel; barriers are 1-wave (near-free) LDS fences.
// ---------------------------------------------------------------
__global__ __launch_bounds__(64, 6) void attn_dpp_kernel(
    const float* __restrict__ q, const float* __restrict__ k,
    const float* __restrict__ v, const float* __restrict__ gate_p,
    float* __restrict__ y)
{
    const int lane = threadIdx.x;
    const int z = blockIdx.x;            // 0..255
    const int n = blockIdx.y;
    const float* kh = k + (size_t)n * SEQ * HDIM;
    const float* vh = v + (size_t)n * SEQ * HDIM;

    __shared__ float  simprob[SEQ];      // sim row, later softmax numerators
    __shared__ double gram[17][17];
    __shared__ int    eidx[17];
    __shared__ float  ystd_s[HDIM];

    const float gp = gate_p[0];
    const float gate = 1.f / (1.f + expf(-gp));
    const float scale = 0.125f;          // 1/sqrt(64)

    for (int rep = 0; rep < 2; ++rep) {
        const int i = rep ? (SEQ - 1 - z) : z;

        // ---- phase 1: sim row. 16 rows/iter, dot split over 4-lane groups,
        //      q quarter held in registers. ----
        {
            const int c  = lane & 3;     // dim quarter
            const int rg = lane >> 2;    // row-in-group
            const float4* qp = (const float4*)(q + ((size_t)n * SEQ + i) * HDIM + c * 16);
            float4 q0 = qp[0], q1 = qp[1], q2 = qp[2], q3 = qp[3];
            const int ng16 = (i >> 4) + 1;
            for (int g = 0; g < ng16; ++g) {
                int row = (g << 4) + rg;
                const float4* kr = (const float4*)(kh + row * HDIM + c * 16);
                float4 k0 = kr[0], k1 = kr[1], k2 = kr[2], k3 = kr[3];
                float s = 0.f;
                s = fmaf(q0.x, k0.x, s); s = fmaf(q0.y, k0.y, s);
                s = fmaf(q0.z, k0.z, s); s = fmaf(q0.w, k0.w, s);
                s = fmaf(q1.x, k1.x, s); s = fmaf(q1.y, k1.y, s);
                s = fmaf(q1.z, k1.z, s); s = fmaf(q1.w, k1.w, s);
                s = fmaf(q2.x, k2.x, s); s = fmaf(q2.y, k2.y, s);
                s = fmaf(q2.z, k2.z, s); s = fmaf(q2.w, k2.w, s);
                s = fmaf(q3.x, k3.x, s); s = fmaf(q3.y, k3.y, s);
                s = fmaf(q3.z, k3.z, s); s = fmaf(q3.w, k3.w, s);
                s += __shfl_xor(s, 1);
                s += __shfl_xor(s, 2);
                if (c == 0 && row <= i) simprob[row] = s;
            }
        }
        __syncthreads();

        // ---- phase 2: load sim to regs (masked), top-16, softmax stats ----
        float sim8[8];
        #pragma unroll
        for (int m = 0; m < 8; ++m) {
            int j = lane + (m << 6);
            sim8[m] = (j <= i) ? simprob[j] : NEGINF;
        }
        {
            float vals[8];
            #pragma unroll
            for (int m = 0; m < 8; ++m) vals[m] = sim8[m];
            if (lane == 0) eidx[0] = i;
            #pragma unroll
            for (int s = 0; s < TOPM; ++s) {
                float bv = vals[0]; int bi = lane;
                #pragma unroll
                for (int m = 1; m < 8; ++m)
                    if (vals[m] > bv) { bv = vals[m]; bi = lane + (m << 6); }
                float rv = bv; int ri = bi;
                #pragma unroll
                for (int off = 32; off; off >>= 1) {
                    float ov = __shfl_xor(rv, off);
                    int   oi = __shfl_xor(ri, off);
                    if (ov > rv || (ov == rv && oi < ri)) { rv = ov; ri = oi; }
                }
                if (lane == 0) eidx[1 + s] = ri;
                if ((ri & 63) == lane) {
                    int om = ri >> 6;
                    #pragma unroll
                    for (int m = 0; m < 8; ++m) if (m == om) vals[m] = -2e30f;
                }
            }
        }
        float lm = -3e38f;
        #pragma unroll
        for (int m = 0; m < 8; ++m) lm = fmaxf(lm, sim8[m]);
        #pragma unroll
        for (int off = 32; off; off >>= 1) lm = fmaxf(lm, __shfl_xor(lm, off));
        const float mx = lm * scale;
        float sum = 0.f;
        float p8[8];
        #pragma unroll
        for (int m = 0; m < 8; ++m) {
            float p = expf(sim8[m] * scale - mx);  // 0 for masked
            p8[m] = p;
            sum += p;
        }
        #pragma unroll
        for (int off = 32; off; off >>= 1) sum += __shfl_xor(sum, off);
        const float denom = sum;
        __syncthreads();   // eidx visible; sim reads done before overwrite
        #pragma unroll
        for (int m = 0; m < 8; ++m) simprob[lane + (m << 6)] = p8[m];
        __syncthreads();

        // ---- phase 3: 17x17 fp64 Gram via triangular symmetry ----
        for (int e = lane; e < 153; e += 64) {
            int a = 0, start = 0;
            while (start + a + 1 <= e) { start += a + 1; ++a; }
            int b = e - start;
            const float4* ka4 = (const float4*)(kh + eidx[a] * HDIM);
            const float4* kb4 = (const float4*)(kh + eidx[b] * HDIM);
            double s = 0.0;
            #pragma unroll
            for (int d4 = 0; d4 < 16; ++d4) {
                float4 av = ka4[d4], bv = kb4[d4];
                s += (double)av.x * bv.x + (double)av.y * bv.y
                   + (double)av.z * bv.z + (double)av.w * bv.w;
            }
            gram[a][b] = s;
            gram[b][a] = s;
        }
        __syncthreads();

        // ---- phase 4: greedy DPP via incremental Cholesky ----
        int selI[SMAX];
        int sc = 1;
        {
            const int c = lane;
            const bool isCand = (c < TOPM);
            const int nvalid = (i + 1 < TOPM) ? (i + 1) : TOPM;
            bool active = isCand && (c < nvalid) && (eidx[1 + c] != i);
            double zc[7];
            #pragma unroll
            for (int t = 0; t < 7; ++t) zc[t] = 0.0;
            double det = gram[0][0];
            double cur = log(det + 1e-6);
            double cnorm = isCand ? gram[1 + c][1 + c] : 0.0;
            double L00 = sqrt(det > 0.0 ? det : 1e-30);
            if (isCand) zc[0] = gram[1 + c][0] / L00;
            #pragma unroll
            for (int t = 0; t < SMAX; ++t) selI[t] = i;

            for (int it = 0; it < SMAX - 1; ++it) {
                double dc = cnorm;
                #pragma unroll
                for (int t = 0; t < 7; ++t) if (t < sc) dc -= zc[t] * zc[t];
                double arg = det * dc + 1e-6;
                // arg<=0: ref's fp32 log -> NaN wins jnp.argmax; mimic with +huge
                double score = (arg > 0.0) ? log(arg) / (double)(sc + 1) : 1e31;
                double rv2 = active ? score : -1e30;
                int rc = c;
                #pragma unroll
                for (int off = 32; off; off >>= 1) {
                    double ov = __shfl_xor(rv2, off);
                    int    oc = __shfl_xor(rc, off);
                    if (ov > rv2 || (ov == rv2 && oc < rc)) { rv2 = ov; rc = oc; }
                }
                bool any = (__any(active ? 1 : 0) != 0);
                bool take = any && ((rv2 > cur) || (sc < 4));
                if (!take) break;

                double dbest = __shfl(dc, rc);
                double Lss = sqrt(dbest > 1e-30 ? dbest : 1e-30);
                double zb[7];
                #pragma unroll
                for (int t = 0; t < 7; ++t) zb[t] = __shfl(zc[t], rc);
                if (isCand) {
                    double crossn = gram[1 + c][1 + rc];
                    double s2 = 0.0;
                    #pragma unroll
                    for (int t = 0; t < 7; ++t) if (t < sc) s2 += zc[t] * zb[t];
                    double znew = (crossn - s2) / Lss;
                    #pragma unroll
                    for (int t = 0; t < 7; ++t) if (t == sc) zc[t] = znew;
                }
                det = det * dbest;
                cur = rv2;
                if (c == rc) active = false;
                int newIdx = eidx[1 + rc];
                #pragma unroll
                for (int t = 0; t < SMAX; ++t) if (t == sc) selI[t] = newIdx;
                ++sc;
            }
        }

        // ---- phase 5: PV (float4, 4 rows/iter), DPP combine, store ----
        {
            const int g4 = lane >> 4;    // row offset in 4-group
            const int qd = lane & 15;    // d-quad
            float4 acc = {0.f, 0.f, 0.f, 0.f};
            const int n4 = (i >> 2) + 1;
            #pragma unroll 4
            for (int j4 = 0; j4 < n4; ++j4) {
                int row = (j4 << 2) + g4;
                float p = simprob[row];  // 0 beyond i (masked numerators)
                float4 vv = *(const float4*)(vh + row * HDIM + (qd << 2));
                acc.x = fmaf(p, vv.x, acc.x);
                acc.y = fmaf(p, vv.y, acc.y);
                acc.z = fmaf(p, vv.z, acc.z);
                acc.w = fmaf(p, vv.w, acc.w);
            }
            acc.x += __shfl_xor(acc.x, 16); acc.y += __shfl_xor(acc.y, 16);
            acc.z += __shfl_xor(acc.z, 16); acc.w += __shfl_xor(acc.w, 16);
            acc.x += __shfl_xor(acc.x, 32); acc.y += __shfl_xor(acc.y, 32);
            acc.z += __shfl_xor(acc.z, 32); acc.w += __shfl_xor(acc.w, 32);
            if (lane < 16) *(float4*)&ystd_s[lane << 2] = acc;
        }
        __syncthreads();
        {
            const float ystd = ystd_s[lane] / denom;
            // DPP weights: softmax over subset == p[sel]/sum(p[sel])
            float wsum = 0.f;
            #pragma unroll
            for (int s = 0; s < SMAX; ++s) if (s < sc) wsum += simprob[selI[s]];
            float yd = 0.f;
            #pragma unroll
            for (int s = 0; s < SMAX; ++s)
                if (s < sc) yd = fmaf(simprob[selI[s]], vh[selI[s] * HDIM + lane], yd);
            yd /= wsum;
            y[((size_t)n * SEQ + i) * HDIM + lane] = gate * yd + (1.f - gate) * ystd;
        }
        __syncthreads();   // protect simprob/gram before next rep
    }
}

// ---------------------------------------------------------------
// Kernel 3: out = reshape(y) @ w_proj + b_proj (gathered A)
// ---------------------------------------------------------------
__global__ __launch_bounds__(256) void proj_gemm_kernel(
    const float* __restrict__ y, const float* __restrict__ w,
    const float* __restrict__ bias, float* __restrict__ out)
{
    __shared__ float As[16][68];
    __shared__ float Bs[16][68];
    const int bm = blockIdx.y * 64;
    const int bn = blockIdx.x * 64;
    const int tid = threadIdx.x;
    const int tm = (tid >> 4) << 2;
    const int tn = (tid & 15) << 2;
    const int lm = tid >> 2;
    const int lkq = (tid & 3) << 2;
    const int lkk = tid >> 4;
    const int lnq = (tid & 15) << 2;
    float acc[4][4] = {};
    for (int k0 = 0; k0 < CDIM; k0 += 16) {
        int row = bm + lm;
        int col = k0 + lkq;
        int b_ = row >> 9, t = row & 511;
        int h = col >> 6, d = col & 63;
        float4 av = *(const float4*)(y + (((b_ * NHEAD + h) * SEQ) + t) * HDIM + d);
        float4 bv = *(const float4*)(w + (k0 + lkk) * CDIM + bn + lnq);
        As[lkq + 0][lm] = av.x;
        As[lkq + 1][lm] = av.y;
        As[lkq + 2][lm] = av.z;
        As[lkq + 3][lm] = av.w;
        *(float4*)&Bs[lkk][lnq] = bv;
        __syncthreads();
        #pragma unroll
        for (int kk = 0; kk < 16; ++kk) {
            float4 a4 = *(const float4*)&As[kk][tm];
            float4 b4 = *(const float4*)&Bs[kk][tn];
            float a[4] = {a4.x, a4.y, a4.z, a4.w};
            float b[4] = {b4.x, b4.y, b4.z, b4.w};
            #pragma unroll
            for (int u = 0; u < 4; ++u)
                #pragma unroll
                for (int w2 = 0; w2 < 4; ++w2)
                    acc[u][w2] = fmaf(a[u], b[w2], acc[u][w2]);
        }
        __syncthreads();
    }
    #pragma unroll
    for (int u = 0; u < 4; ++u) {
        int m = bm + tm + u;
        #pragma unroll
        for (int w2 = 0; w2 < 4; ++w2) {
            int cc = bn + tn + w2;
            out[m * CDIM + cc] = acc[u][w2] + bias[cc];
        }
    }
}

extern "C" void kernel_launch(void* const* d_in, const int* in_sizes, int n_in,
                              void* d_out, int out_size, void* d_ws, size_t ws_size,
                              hipStream_t stream)
{
    const float* x      = (const float*)d_in[0];
    const float* w_qkv  = (const float*)d_in[1];
    const float* b_qkv  = (const float*)d_in[2];
    const float* w_proj = (const float*)d_in[3];
    const float* b_proj = (const float*)d_in[4];
    const float* gate_p = (const float*)d_in[5];
    float* out = (float*)d_out;

    float* ws = (float*)d_ws;
    const size_t HS = (size_t)NBATCH * NHEAD * SEQ * HDIM;  // 786432
    float* q = ws;
    float* k = q + HS;
    float* v = k + HS;
    float* y = v + HS;

    qkv_gemm_kernel<<<dim3((3 * CDIM) / 64, (NBATCH * SEQ) / 64), 256, 0, stream>>>(
        x, w_qkv, b_qkv, q, k, v);
    attn_dpp_kernel<<<dim3(SEQ / 2, NBATCH * NHEAD), 64, 0, stream>>>(
        q, k, v, gate_p, y);
    proj_gemm_kernel<<<dim3(CDIM / 64, (NBATCH * SEQ) / 64), 256, 0, stream>>>(
        y, w_proj, b_proj, out);
}

// Round 4
// 284.115 us; speedup vs baseline: 2.4996x; 1.2155x over previous
//
#include <hip/hip_runtime.h>
#include <math.h>

// Problem constants
constexpr int SEQ   = 512;
constexpr int HDIM  = 64;
constexpr int NHEAD = 12;
constexpr int NBATCH = 2;
constexpr int CDIM  = 768;
constexpr int TOPM  = 16;
constexpr int SMAX  = 8;
constexpr float NEGINF = -1e30f;

// ---------------------------------------------------------------
// Kernel 1: QKV = x @ w_qkv + b_qkv, scattered to q/k/v [24,512,64]
// ---------------------------------------------------------------
__global__ __launch_bounds__(256) void qkv_gemm_kernel(
    const float* __restrict__ x, const float* __restrict__ w,
    const float* __restrict__ bias,
    float* __restrict__ q, float* __restrict__ k, float* __restrict__ v)
{
    __shared__ float As[16][68];
    __shared__ float Bs[16][68];
    const int bm = blockIdx.y * 64;
    const int bn = blockIdx.x * 64;
    const int tid = threadIdx.x;
    const int tm = (tid >> 4) << 2;
    const int tn = (tid & 15) << 2;
    const int lm = tid >> 2;
    const int lkq = (tid & 3) << 2;
    const int lkk = tid >> 4;
    const int lnq = (tid & 15) << 2;
    float acc[4][4] = {};
    for (int k0 = 0; k0 < CDIM; k0 += 16) {
        float4 av = *(const float4*)(x + (bm + lm) * CDIM + k0 + lkq);
        float4 bv = *(const float4*)(w + (k0 + lkk) * (3 * CDIM) + bn + lnq);
        As[lkq + 0][lm] = av.x;
        As[lkq + 1][lm] = av.y;
        As[lkq + 2][lm] = av.z;
        As[lkq + 3][lm] = av.w;
        *(float4*)&Bs[lkk][lnq] = bv;
        __syncthreads();
        #pragma unroll
        for (int kk = 0; kk < 16; ++kk) {
            float4 a4 = *(const float4*)&As[kk][tm];
            float4 b4 = *(const float4*)&Bs[kk][tn];
            float a[4] = {a4.x, a4.y, a4.z, a4.w};
            float b[4] = {b4.x, b4.y, b4.z, b4.w};
            #pragma unroll
            for (int u = 0; u < 4; ++u)
                #pragma unroll
                for (int w2 = 0; w2 < 4; ++w2)
                    acc[u][w2] = fmaf(a[u], b[w2], acc[u][w2]);
        }
        __syncthreads();
    }
    #pragma unroll
    for (int u = 0; u < 4; ++u) {
        int m = bm + tm + u;
        int b_ = m >> 9, t = m & 511;
        #pragma unroll
        for (int w2 = 0; w2 < 4; ++w2) {
            int cc = bn + tn + w2;
            float val = acc[u][w2] + bias[cc];
            int part = cc / CDIM;
            int c2 = cc - part * CDIM;
            int h = c2 >> 6, d = c2 & 63;
            float* dst = (part == 0) ? q : ((part == 1) ? k : v);
            dst[(((b_ * NHEAD + h) * SEQ) + t) * HDIM + d] = val;
        }
    }
}

// ---------------------------------------------------------------
// Kernel 2: S[n,i,j] = q_i . k_j  (fp32, lower-triangular tiles only)
// 64x64 tiles, K-dim = 64 fully staged in LDS (transposed).
// ---------------------------------------------------------------
__global__ __launch_bounds__(256) void sgemm_qk_kernel(
    const float* __restrict__ q, const float* __restrict__ k,
    float* __restrict__ S)
{
    __shared__ float Qs[64][68];   // [d][token_i]
    __shared__ float Ks[64][68];   // [d][token_j]
    const int e = blockIdx.x;      // 0..35 lower-tri tile
    const int n = blockIdx.y;
    int it = 0, start = 0;
    while (start + it + 1 <= e) { start += it + 1; ++it; }
    const int jt = e - start;
    const int tid = threadIdx.x;
    const float* qh = q + (size_t)n * SEQ * HDIM;
    const float* kh = k + (size_t)n * SEQ * HDIM;

    #pragma unroll
    for (int l = 0; l < 4; ++l) {
        int idx = tid + l * 256;             // 0..1023
        int tok = idx >> 4, q4 = (idx & 15) << 2;
        float4 qv = *(const float4*)(qh + (it * 64 + tok) * HDIM + q4);
        Qs[q4 + 0][tok] = qv.x; Qs[q4 + 1][tok] = qv.y;
        Qs[q4 + 2][tok] = qv.z; Qs[q4 + 3][tok] = qv.w;
        float4 kv = *(const float4*)(kh + (jt * 64 + tok) * HDIM + q4);
        Ks[q4 + 0][tok] = kv.x; Ks[q4 + 1][tok] = kv.y;
        Ks[q4 + 2][tok] = kv.z; Ks[q4 + 3][tok] = kv.w;
    }
    __syncthreads();

    const int tm = (tid >> 4) << 2;
    const int tn = (tid & 15) << 2;
    float acc[4][4] = {};
    #pragma unroll
    for (int d = 0; d < 64; ++d) {
        float4 a4 = *(const float4*)&Qs[d][tm];
        float4 b4 = *(const float4*)&Ks[d][tn];
        float a[4] = {a4.x, a4.y, a4.z, a4.w};
        float b[4] = {b4.x, b4.y, b4.z, b4.w};
        #pragma unroll
        for (int u = 0; u < 4; ++u)
            #pragma unroll
            for (int w2 = 0; w2 < 4; ++w2)
                acc[u][w2] = fmaf(a[u], b[w2], acc[u][w2]);
    }
    #pragma unroll
    for (int u = 0; u < 4; ++u) {
        int i = it * 64 + tm + u;
        float4 o = {acc[u][0], acc[u][1], acc[u][2], acc[u][3]};
        *(float4*)(S + ((size_t)n * SEQ + i) * SEQ + jt * 64 + tn) = o;
    }
}

// ---------------------------------------------------------------
// Kernel 3: per-token DPP. Reads S row -> softmax numerators (stored
// in-place as P), top-16, fp64 Gram, greedy Cholesky, DPP combine.
// One wave per token, 4 tokens per block.
// ---------------------------------------------------------------
__global__ __launch_bounds__(256) void dpp_kernel(
    const float* __restrict__ k, const float* __restrict__ v,
    float* __restrict__ S, const float* __restrict__ gate_p,
    float* __restrict__ ydppw, float* __restrict__ denomArr)
{
    const int tid  = threadIdx.x;
    const int wid  = tid >> 6;
    const int lane = tid & 63;
    const int i = blockIdx.x * 4 + wid;
    const int n = blockIdx.y;
    const float* kh = k + (size_t)n * SEQ * HDIM;
    const float* vh = v + (size_t)n * SEQ * HDIM;
    float* Srow = S + ((size_t)n * SEQ + i) * SEQ;

    __shared__ float  prow[4][SEQ];
    __shared__ double gram[4][17][17];
    __shared__ int    eidx[4][17];

    // ---- load sim row (masked) ----
    float sim8[8];
    #pragma unroll
    for (int m = 0; m < 8; ++m) {
        int j = lane + (m << 6);
        sim8[m] = (j <= i) ? Srow[j] : NEGINF;
    }

    // ---- top-16 (stable ties = lowest index, matching lax.top_k) ----
    {
        float vals[8];
        #pragma unroll
        for (int m = 0; m < 8; ++m) vals[m] = sim8[m];
        if (lane == 0) eidx[wid][0] = i;
        #pragma unroll
        for (int s = 0; s < TOPM; ++s) {
            float bv = vals[0]; int bi = lane;
            #pragma unroll
            for (int m = 1; m < 8; ++m)
                if (vals[m] > bv) { bv = vals[m]; bi = lane + (m << 6); }
            float rv = bv; int ri = bi;
            #pragma unroll
            for (int off = 32; off; off >>= 1) {
                float ov = __shfl_xor(rv, off);
                int   oi = __shfl_xor(ri, off);
                if (ov > rv || (ov == rv && oi < ri)) { rv = ov; ri = oi; }
            }
            if (lane == 0) eidx[wid][1 + s] = ri;
            if ((ri & 63) == lane) {
                int om = ri >> 6;
                #pragma unroll
                for (int m = 0; m < 8; ++m) if (m == om) vals[m] = -2e30f;
            }
        }
    }

    // ---- softmax stats; write numerators to LDS + global (P over S) ----
    const float scale = 0.125f;
    float lm = -3e38f;
    #pragma unroll
    for (int m = 0; m < 8; ++m) lm = fmaxf(lm, sim8[m]);
    #pragma unroll
    for (int off = 32; off; off >>= 1) lm = fmaxf(lm, __shfl_xor(lm, off));
    const float mx = lm * scale;
    float sum = 0.f;
    #pragma unroll
    for (int m = 0; m < 8; ++m) {
        float p = expf(sim8[m] * scale - mx);   // 0 for masked entries
        int j = lane + (m << 6);
        prow[wid][j] = p;
        Srow[j] = p;
        sum += p;
    }
    #pragma unroll
    for (int off = 32; off; off >>= 1) sum += __shfl_xor(sum, off);
    const float denom = sum;
    __syncthreads();

    // ---- 17x17 fp64 Gram via triangular symmetry (153 dots) ----
    for (int e = lane; e < 153; e += 64) {
        int a = 0, st = 0;
        while (st + a + 1 <= e) { st += a + 1; ++a; }
        int b = e - st;
        const float4* ka4 = (const float4*)(kh + eidx[wid][a] * HDIM);
        const float4* kb4 = (const float4*)(kh + eidx[wid][b] * HDIM);
        double s = 0.0;
        #pragma unroll
        for (int d4 = 0; d4 < 16; ++d4) {
            float4 av = ka4[d4], bv = kb4[d4];
            s += (double)av.x * bv.x + (double)av.y * bv.y
               + (double)av.z * bv.z + (double)av.w * bv.w;
        }
        gram[wid][a][b] = s;
        gram[wid][b][a] = s;
    }
    __syncthreads();

    // ---- greedy DPP via incremental Cholesky ----
    int selI[SMAX];
    int sc = 1;
    {
        const int c = lane;
        const bool isCand = (c < TOPM);
        const int nvalid = (i + 1 < TOPM) ? (i + 1) : TOPM;
        bool active = isCand && (c < nvalid) && (eidx[wid][1 + c] != i);
        double zc[7];
        #pragma unroll
        for (int t = 0; t < 7; ++t) zc[t] = 0.0;
        double det = gram[wid][0][0];
        double cur = log(det + 1e-6);
        double cnorm = isCand ? gram[wid][1 + c][1 + c] : 0.0;
        double L00 = sqrt(det > 0.0 ? det : 1e-30);
        if (isCand) zc[0] = gram[wid][1 + c][0] / L00;
        #pragma unroll
        for (int t = 0; t < SMAX; ++t) selI[t] = i;

        for (int it = 0; it < SMAX - 1; ++it) {
            double dc = cnorm;
            #pragma unroll
            for (int t = 0; t < 7; ++t) if (t < sc) dc -= zc[t] * zc[t];
            double arg = det * dc + 1e-6;
            // arg<=0: ref's fp32 log -> NaN wins jnp.argmax; mimic with +huge
            double score = (arg > 0.0) ? log(arg) / (double)(sc + 1) : 1e31;
            double rv2 = active ? score : -1e30;
            int rc = c;
            #pragma unroll
            for (int off = 32; off; off >>= 1) {
                double ov = __shfl_xor(rv2, off);
                int    oc = __shfl_xor(rc, off);
                if (ov > rv2 || (ov == rv2 && oc < rc)) { rv2 = ov; rc = oc; }
            }
            bool any = (__any(active ? 1 : 0) != 0);
            bool take = any && ((rv2 > cur) || (sc < 4));
            if (!take) break;

            double dbest = __shfl(dc, rc);
            double Lss = sqrt(dbest > 1e-30 ? dbest : 1e-30);
            double zb[7];
            #pragma unroll
            for (int t = 0; t < 7; ++t) zb[t] = __shfl(zc[t], rc);
            if (isCand) {
                double crossn = gram[wid][1 + c][1 + rc];
                double s2 = 0.0;
                #pragma unroll
                for (int t = 0; t < 7; ++t) if (t < sc) s2 += zc[t] * zb[t];
                double znew = (crossn - s2) / Lss;
                #pragma unroll
                for (int t = 0; t < 7; ++t) if (t == sc) zc[t] = znew;
            }
            det = det * dbest;
            cur = rv2;
            if (c == rc) active = false;
            int newIdx = eidx[wid][1 + rc];
            #pragma unroll
            for (int t = 0; t < SMAX; ++t) if (t == sc) selI[t] = newIdx;
            ++sc;
        }
    }

    // ---- DPP combine: yd = sum p[sel] v[sel] / sum p[sel]; store gated ----
    float wsum = 0.f;
    #pragma unroll
    for (int s = 0; s < SMAX; ++s) if (s < sc) wsum += prow[wid][selI[s]];
    float yd = 0.f;
    #pragma unroll
    for (int s = 0; s < SMAX; ++s)
        if (s < sc) yd = fmaf(prow[wid][selI[s]], vh[selI[s] * HDIM + lane], yd);
    const float gp = gate_p[0];
    const float gate = 1.f / (1.f + expf(-gp));
    ydppw[((size_t)n * SEQ + i) * HDIM + lane] = gate * yd / wsum;
    if (lane == 0) denomArr[n * SEQ + i] = denom;
}

// ---------------------------------------------------------------
// Kernel 4: ystd = (P @ V)/denom, fused gate-merge with ydppw.
// 64x64 output tiles, j-chunks of 32 with causal skipping.
// ---------------------------------------------------------------
__global__ __launch_bounds__(256) void pv_gemm_kernel(
    const float* __restrict__ P, const float* __restrict__ v,
    const float* __restrict__ ydppw, const float* __restrict__ denomArr,
    const float* __restrict__ gate_p, float* __restrict__ y)
{
    __shared__ float Ps[32][68];   // [j][token]
    __shared__ float Vs[32][68];   // [j][d]
    const int tt = blockIdx.x;     // token tile 0..7
    const int n  = blockIdx.y;
    const int t0 = tt * 64;
    const int tid = threadIdx.x;
    const float* Ph = P + (size_t)n * SEQ * SEQ;
    const float* vh = v + (size_t)n * SEQ * HDIM;
    const int tm = (tid >> 4) << 2;   // token offset
    const int tn = (tid & 15) << 2;   // d offset
    float acc[4][4] = {};
    const int jmax = t0 + 64;
    for (int j0 = 0; j0 < jmax; j0 += 32) {
        #pragma unroll
        for (int l = 0; l < 2; ++l) {
            int idx = tid + l * 256;          // 0..511
            int tok = idx >> 3, j4 = (idx & 7) << 2;
            float4 p4 = *(const float4*)(Ph + (t0 + tok) * SEQ + j0 + j4);
            Ps[j4 + 0][tok] = p4.x; Ps[j4 + 1][tok] = p4.y;
            Ps[j4 + 2][tok] = p4.z; Ps[j4 + 3][tok] = p4.w;
        }
        #pragma unroll
        for (int l = 0; l < 2; ++l) {
            int idx = tid + l * 256;
            int j = idx >> 4, d4 = (idx & 15) << 2;
            *(float4*)&Vs[j][d4] = *(const float4*)(vh + (j0 + j) * HDIM + d4);
        }
        __syncthreads();
        #pragma unroll
        for (int j = 0; j < 32; ++j) {
            float4 a4 = *(const float4*)&Ps[j][tm];
            float4 b4 = *(const float4*)&Vs[j][tn];
            float a[4] = {a4.x, a4.y, a4.z, a4.w};
            float b[4] = {b4.x, b4.y, b4.z, b4.w};
            #pragma unroll
            for (int u = 0; u < 4; ++u)
                #pragma unroll
                for (int w2 = 0; w2 < 4; ++w2)
                    acc[u][w2] = fmaf(a[u], b[w2], acc[u][w2]);
        }
        __syncthreads();
    }
    const float gp = gate_p[0];
    const float gate = 1.f / (1.f + expf(-gp));
    #pragma unroll
    for (int u = 0; u < 4; ++u) {
        int i = t0 + tm + u;
        float den = denomArr[n * SEQ + i];
        #pragma unroll
        for (int w2 = 0; w2 < 4; ++w2) {
            int d = tn + w2;
            size_t off = ((size_t)n * SEQ + i) * HDIM + d;
            y[off] = ydppw[off] + (1.f - gate) * acc[u][w2] / den;
        }
    }
}

// ---------------------------------------------------------------
// Kernel 5: out = reshape(y) @ w_proj + b_proj (gathered A)
// ---------------------------------------------------------------
__global__ __launch_bounds__(256) void proj_gemm_kernel(
    const float* __restrict__ y, const float* __restrict__ w,
    const float* __restrict__ bias, float* __restrict__ out)
{
    __shared__ float As[16][68];
    __shared__ float Bs[16][68];
    const int bm = blockIdx.y * 64;
    const int bn = blockIdx.x * 64;
    const int tid = threadIdx.x;
    const int tm = (tid >> 4) << 2;
    const int tn = (tid & 15) << 2;
    const int lm = tid >> 2;
    const int lkq = (tid & 3) << 2;
    const int lkk = tid >> 4;
    const int lnq = (tid & 15) << 2;
    float acc[4][4] = {};
    for (int k0 = 0; k0 < CDIM; k0 += 16) {
        int row = bm + lm;
        int col = k0 + lkq;
        int b_ = row >> 9, t = row & 511;
        int h = col >> 6, d = col & 63;
        float4 av = *(const float4*)(y + (((b_ * NHEAD + h) * SEQ) + t) * HDIM + d);
        float4 bv = *(const float4*)(w + (k0 + lkk) * CDIM + bn + lnq);
        As[lkq + 0][lm] = av.x;
        As[lkq + 1][lm] = av.y;
        As[lkq + 2][lm] = av.z;
        As[lkq + 3][lm] = av.w;
        *(float4*)&Bs[lkk][lnq] = bv;
        __syncthreads();
        #pragma unroll
        for (int kk = 0; kk < 16; ++kk) {
            float4 a4 = *(const float4*)&As[kk][tm];
            float4 b4 = *(const float4*)&Bs[kk][tn];
            float a[4] = {a4.x, a4.y, a4.z, a4.w};
            float b[4] = {b4.x, b4.y, b4.z, b4.w};
            #pragma unroll
            for (int u = 0; u < 4; ++u)
                #pragma unroll
                for (int w2 = 0; w2 < 4; ++w2)
                    acc[u][w2] = fmaf(a[u], b[w2], acc[u][w2]);
        }
        __syncthreads();
    }
    #pragma unroll
    for (int u = 0; u < 4; ++u) {
        int m = bm + tm + u;
        #pragma unroll
        for (int w2 = 0; w2 < 4; ++w2) {
            int cc = bn + tn + w2;
            out[m * CDIM + cc] = acc[u][w2] + bias[cc];
        }
    }
}

extern "C" void kernel_launch(void* const* d_in, const int* in_sizes, int n_in,
                              void* d_out, int out_size, void* d_ws, size_t ws_size,
                              hipStream_t stream)
{
    const float* x      = (const float*)d_in[0];
    const float* w_qkv  = (const float*)d_in[1];
    const float* b_qkv  = (const float*)d_in[2];
    const float* w_proj = (const float*)d_in[3];
    const float* b_proj = (const float*)d_in[4];
    const float* gate_p = (const float*)d_in[5];
    float* out = (float*)d_out;

    float* ws = (float*)d_ws;
    const size_t HS = (size_t)NBATCH * NHEAD * SEQ * HDIM;   // 786432
    const size_t SS = (size_t)NBATCH * NHEAD * SEQ * SEQ;    // 6291456
    float* q     = ws;
    float* k     = q + HS;
    float* v     = k + HS;
    float* y     = v + HS;
    float* S     = y + HS;        // sim matrix, becomes P in-place
    float* ydppw = S + SS;
    float* den   = ydppw + HS;    // 12288 floats

    qkv_gemm_kernel<<<dim3((3 * CDIM) / 64, (NBATCH * SEQ) / 64), 256, 0, stream>>>(
        x, w_qkv, b_qkv, q, k, v);
    sgemm_qk_kernel<<<dim3(36, NBATCH * NHEAD), 256, 0, stream>>>(q, k, S);
    dpp_kernel<<<dim3(SEQ / 4, NBATCH * NHEAD), 256, 0, stream>>>(
        k, v, S, gate_p, ydppw, den);
    pv_gemm_kernel<<<dim3(SEQ / 64, NBATCH * NHEAD), 256, 0, stream>>>(
        S, v, ydppw, den, gate_p, y);
    proj_gemm_kernel<<<dim3(CDIM / 64, (NBATCH * SEQ) / 64), 256, 0, stream>>>(
        y, w_proj, b_proj, out);
}

// Round 5
// 263.162 us; speedup vs baseline: 2.6986x; 1.0796x over previous
//
#include <hip/hip_runtime.h>
#include <math.h>

// Problem constants
constexpr int SEQ   = 512;
constexpr int HDIM  = 64;
constexpr int NHEAD = 12;
constexpr int NBATCH = 2;
constexpr int CDIM  = 768;
constexpr int TOPM  = 16;
constexpr int SMAX  = 8;
constexpr float NEGINF = -1e30f;

// ---------------------------------------------------------------
// Kernel 1: QKV = x @ w_qkv + b_qkv, scattered to q/k/v [24,512,64]
// ---------------------------------------------------------------
__global__ __launch_bounds__(256) void qkv_gemm_kernel(
    const float* __restrict__ x, const float* __restrict__ w,
    const float* __restrict__ bias,
    float* __restrict__ q, float* __restrict__ k, float* __restrict__ v)
{
    __shared__ float As[16][68];
    __shared__ float Bs[16][68];
    const int bm = blockIdx.y * 64;
    const int bn = blockIdx.x * 64;
    const int tid = threadIdx.x;
    const int tm = (tid >> 4) << 2;
    const int tn = (tid & 15) << 2;
    const int lm = tid >> 2;
    const int lkq = (tid & 3) << 2;
    const int lkk = tid >> 4;
    const int lnq = (tid & 15) << 2;
    float acc[4][4] = {};
    for (int k0 = 0; k0 < CDIM; k0 += 16) {
        float4 av = *(const float4*)(x + (bm + lm) * CDIM + k0 + lkq);
        float4 bv = *(const float4*)(w + (k0 + lkk) * (3 * CDIM) + bn + lnq);
        As[lkq + 0][lm] = av.x;
        As[lkq + 1][lm] = av.y;
        As[lkq + 2][lm] = av.z;
        As[lkq + 3][lm] = av.w;
        *(float4*)&Bs[lkk][lnq] = bv;
        __syncthreads();
        #pragma unroll
        for (int kk = 0; kk < 16; ++kk) {
            float4 a4 = *(const float4*)&As[kk][tm];
            float4 b4 = *(const float4*)&Bs[kk][tn];
            float a[4] = {a4.x, a4.y, a4.z, a4.w};
            float b[4] = {b4.x, b4.y, b4.z, b4.w};
            #pragma unroll
            for (int u = 0; u < 4; ++u)
                #pragma unroll
                for (int w2 = 0; w2 < 4; ++w2)
                    acc[u][w2] = fmaf(a[u], b[w2], acc[u][w2]);
        }
        __syncthreads();
    }
    #pragma unroll
    for (int u = 0; u < 4; ++u) {
        int m = bm + tm + u;
        int b_ = m >> 9, t = m & 511;
        #pragma unroll
        for (int w2 = 0; w2 < 4; ++w2) {
            int cc = bn + tn + w2;
            float val = acc[u][w2] + bias[cc];
            int part = cc / CDIM;
            int c2 = cc - part * CDIM;
            int h = c2 >> 6, d = c2 & 63;
            float* dst = (part == 0) ? q : ((part == 1) ? k : v);
            dst[(((b_ * NHEAD + h) * SEQ) + t) * HDIM + d] = val;
        }
    }
}

// ---------------------------------------------------------------
// Kernel 2: S[n,i,j] = q_i . k_j  (fp32, lower-triangular tiles only)
// ---------------------------------------------------------------
__global__ __launch_bounds__(256) void sgemm_qk_kernel(
    const float* __restrict__ q, const float* __restrict__ k,
    float* __restrict__ S)
{
    __shared__ float Qs[64][68];   // [d][token_i]
    __shared__ float Ks[64][68];   // [d][token_j]
    const int e = blockIdx.x;      // 0..35 lower-tri tile
    const int n = blockIdx.y;
    int it = 0, start = 0;
    while (start + it + 1 <= e) { start += it + 1; ++it; }
    const int jt = e - start;
    const int tid = threadIdx.x;
    const float* qh = q + (size_t)n * SEQ * HDIM;
    const float* kh = k + (size_t)n * SEQ * HDIM;

    #pragma unroll
    for (int l = 0; l < 4; ++l) {
        int idx = tid + l * 256;
        int tok = idx >> 4, q4 = (idx & 15) << 2;
        float4 qv = *(const float4*)(qh + (it * 64 + tok) * HDIM + q4);
        Qs[q4 + 0][tok] = qv.x; Qs[q4 + 1][tok] = qv.y;
        Qs[q4 + 2][tok] = qv.z; Qs[q4 + 3][tok] = qv.w;
        float4 kv = *(const float4*)(kh + (jt * 64 + tok) * HDIM + q4);
        Ks[q4 + 0][tok] = kv.x; Ks[q4 + 1][tok] = kv.y;
        Ks[q4 + 2][tok] = kv.z; Ks[q4 + 3][tok] = kv.w;
    }
    __syncthreads();

    const int tm = (tid >> 4) << 2;
    const int tn = (tid & 15) << 2;
    float acc[4][4] = {};
    #pragma unroll
    for (int d = 0; d < 64; ++d) {
        float4 a4 = *(const float4*)&Qs[d][tm];
        float4 b4 = *(const float4*)&Ks[d][tn];
        float a[4] = {a4.x, a4.y, a4.z, a4.w};
        float b[4] = {b4.x, b4.y, b4.z, b4.w};
        #pragma unroll
        for (int u = 0; u < 4; ++u)
            #pragma unroll
            for (int w2 = 0; w2 < 4; ++w2)
                acc[u][w2] = fmaf(a[u], b[w2], acc[u][w2]);
    }
    #pragma unroll
    for (int u = 0; u < 4; ++u) {
        int i = it * 64 + tm + u;
        float4 o = {acc[u][0], acc[u][1], acc[u][2], acc[u][3]};
        *(float4*)(S + ((size_t)n * SEQ + i) * SEQ + jt * 64 + tn) = o;
    }
}

// ---------------------------------------------------------------
// Kernel 2b: KKT packed lower-tri tiles: k_a . k_b (fp64 acc, fp32
// store, single rounding). Tile e=(it,jt), packed as e*4096.
// ---------------------------------------------------------------
__global__ __launch_bounds__(256) void kkt_gemm_kernel(
    const float* __restrict__ k, float* __restrict__ KKT)
{
    __shared__ float Ra[64][68];   // [d][tok] row-tile keys
    __shared__ float Rb[64][68];   // [d][tok] col-tile keys
    const int e = blockIdx.x;      // 0..35
    const int n = blockIdx.y;
    int it = 0, start = 0;
    while (start + it + 1 <= e) { start += it + 1; ++it; }
    const int jt = e - start;
    const int tid = threadIdx.x;
    const float* kh = k + (size_t)n * SEQ * HDIM;

    #pragma unroll
    for (int l = 0; l < 4; ++l) {
        int idx = tid + l * 256;
        int tok = idx >> 4, q4 = (idx & 15) << 2;
        float4 a = *(const float4*)(kh + (it * 64 + tok) * HDIM + q4);
        Ra[q4 + 0][tok] = a.x; Ra[q4 + 1][tok] = a.y;
        Ra[q4 + 2][tok] = a.z; Ra[q4 + 3][tok] = a.w;
        float4 b = *(const float4*)(kh + (jt * 64 + tok) * HDIM + q4);
        Rb[q4 + 0][tok] = b.x; Rb[q4 + 1][tok] = b.y;
        Rb[q4 + 2][tok] = b.z; Rb[q4 + 3][tok] = b.w;
    }
    __syncthreads();

    const int tm = (tid >> 4) << 2;
    const int tn = (tid & 15) << 2;
    double acc[4][4] = {};
    #pragma unroll 8
    for (int d = 0; d < 64; ++d) {
        float4 a4 = *(const float4*)&Ra[d][tm];
        float4 b4 = *(const float4*)&Rb[d][tn];
        double a[4] = {a4.x, a4.y, a4.z, a4.w};
        double b[4] = {b4.x, b4.y, b4.z, b4.w};
        #pragma unroll
        for (int u = 0; u < 4; ++u)
            #pragma unroll
            for (int w2 = 0; w2 < 4; ++w2)
                acc[u][w2] = fma(a[u], b[w2], acc[u][w2]);
    }
    float* dst = KKT + ((size_t)n * 36 + e) * 4096;
    #pragma unroll
    for (int u = 0; u < 4; ++u) {
        float4 o = {(float)acc[u][0], (float)acc[u][1],
                    (float)acc[u][2], (float)acc[u][3]};
        *(float4*)(dst + (tm + u) * 64 + tn) = o;
    }
}

// ---------------------------------------------------------------
// Kernel 3: per-token DPP. S row -> softmax numerators (in-place P),
// top-16, Gram GATHERED from KKT, greedy Cholesky, gated DPP part
// written to y. One wave per token, 4 tokens per block.
// ---------------------------------------------------------------
__global__ __launch_bounds__(256) void dpp_kernel(
    const float* __restrict__ v, float* __restrict__ S,
    const float* __restrict__ KKT, const float* __restrict__ gate_p,
    float* __restrict__ y, float* __restrict__ denomArr)
{
    const int tid  = threadIdx.x;
    const int wid  = tid >> 6;
    const int lane = tid & 63;
    const int i = blockIdx.x * 4 + wid;
    const int n = blockIdx.y;
    const float* vh = v + (size_t)n * SEQ * HDIM;
    const float* KKTh = KKT + (size_t)n * 36 * 4096;
    float* Srow = S + ((size_t)n * SEQ + i) * SEQ;

    __shared__ float  prow[4][SEQ];
    __shared__ double gram[4][17][17];
    __shared__ int    eidx[4][17];

    // ---- load sim row (masked) ----
    float sim8[8];
    #pragma unroll
    for (int m = 0; m < 8; ++m) {
        int j = lane + (m << 6);
        sim8[m] = (j <= i) ? Srow[j] : NEGINF;
    }

    // ---- top-16 (stable ties = lowest index, matching lax.top_k) ----
    {
        float vals[8];
        #pragma unroll
        for (int m = 0; m < 8; ++m) vals[m] = sim8[m];
        if (lane == 0) eidx[wid][0] = i;
        #pragma unroll
        for (int s = 0; s < TOPM; ++s) {
            float bv = vals[0]; int bi = lane;
            #pragma unroll
            for (int m = 1; m < 8; ++m)
                if (vals[m] > bv) { bv = vals[m]; bi = lane + (m << 6); }
            float rv = bv; int ri = bi;
            #pragma unroll
            for (int off = 32; off; off >>= 1) {
                float ov = __shfl_xor(rv, off);
                int   oi = __shfl_xor(ri, off);
                if (ov > rv || (ov == rv && oi < ri)) { rv = ov; ri = oi; }
            }
            if (lane == 0) eidx[wid][1 + s] = ri;
            if ((ri & 63) == lane) {
                int om = ri >> 6;
                #pragma unroll
                for (int m = 0; m < 8; ++m) if (m == om) vals[m] = -2e30f;
            }
        }
    }

    // ---- softmax stats; write numerators to LDS + global (P over S) ----
    const float scale = 0.125f;
    float lm = -3e38f;
    #pragma unroll
    for (int m = 0; m < 8; ++m) lm = fmaxf(lm, sim8[m]);
    #pragma unroll
    for (int off = 32; off; off >>= 1) lm = fmaxf(lm, __shfl_xor(lm, off));
    const float mx = lm * scale;
    float sum = 0.f;
    #pragma unroll
    for (int m = 0; m < 8; ++m) {
        float p = expf(sim8[m] * scale - mx);   // 0 for masked entries
        int j = lane + (m << 6);
        prow[wid][j] = p;
        Srow[j] = p;
        sum += p;
    }
    #pragma unroll
    for (int off = 32; off; off >>= 1) sum += __shfl_xor(sum, off);
    const float denom = sum;
    __syncthreads();

    // ---- 17x17 Gram: GATHER from precomputed KKT (153 scalar loads) ----
    for (int e = lane; e < 153; e += 64) {
        int a = 0, st = 0;
        while (st + a + 1 <= e) { st += a + 1; ++a; }
        int b = e - st;
        int ra = eidx[wid][a], rb = eidx[wid][b];
        int row = ra > rb ? ra : rb;
        int col = ra > rb ? rb : ra;
        int itt = row >> 6, jtt = col >> 6;
        int p = ((itt * (itt + 1)) >> 1) + jtt;
        double s = (double)KKTh[((size_t)p * 64 + (row & 63)) * 64 + (col & 63)];
        gram[wid][a][b] = s;
        gram[wid][b][a] = s;
    }
    __syncthreads();

    // ---- greedy DPP via incremental Cholesky ----
    int selI[SMAX];
    int sc = 1;
    {
        const int c = lane;
        const bool isCand = (c < TOPM);
        const int nvalid = (i + 1 < TOPM) ? (i + 1) : TOPM;
        bool active = isCand && (c < nvalid) && (eidx[wid][1 + c] != i);
        double zc[7];
        #pragma unroll
        for (int t = 0; t < 7; ++t) zc[t] = 0.0;
        double det = gram[wid][0][0];
        double cur = log(det + 1e-6);
        double cnorm = isCand ? gram[wid][1 + c][1 + c] : 0.0;
        double L00 = sqrt(det > 0.0 ? det : 1e-30);
        if (isCand) zc[0] = gram[wid][1 + c][0] / L00;
        #pragma unroll
        for (int t = 0; t < SMAX; ++t) selI[t] = i;

        for (int it = 0; it < SMAX - 1; ++it) {
            double dc = cnorm;
            #pragma unroll
            for (int t = 0; t < 7; ++t) if (t < sc) dc -= zc[t] * zc[t];
            double arg = det * dc + 1e-6;
            // arg<=0: ref's fp32 log -> NaN wins jnp.argmax; mimic with +huge
            double score = (arg > 0.0) ? log(arg) / (double)(sc + 1) : 1e31;
            double rv2 = active ? score : -1e30;
            int rc = c;
            #pragma unroll
            for (int off = 32; off; off >>= 1) {
                double ov = __shfl_xor(rv2, off);
                int    oc = __shfl_xor(rc, off);
                if (ov > rv2 || (ov == rv2 && oc < rc)) { rv2 = ov; rc = oc; }
            }
            bool any = (__any(active ? 1 : 0) != 0);
            bool take = any && ((rv2 > cur) || (sc < 4));
            if (!take) break;

            double dbest = __shfl(dc, rc);
            double Lss = sqrt(dbest > 1e-30 ? dbest : 1e-30);
            double zb[7];
            #pragma unroll
            for (int t = 0; t < 7; ++t) zb[t] = __shfl(zc[t], rc);
            if (isCand) {
                double crossn = gram[wid][1 + c][1 + rc];
                double s2 = 0.0;
                #pragma unroll
                for (int t = 0; t < 7; ++t) if (t < sc) s2 += zc[t] * zb[t];
                double znew = (crossn - s2) / Lss;
                #pragma unroll
                for (int t = 0; t < 7; ++t) if (t == sc) zc[t] = znew;
            }
            det = det * dbest;
            cur = rv2;
            if (c == rc) active = false;
            int newIdx = eidx[wid][1 + rc];
            #pragma unroll
            for (int t = 0; t < SMAX; ++t) if (t == sc) selI[t] = newIdx;
            ++sc;
        }
    }

    // ---- gated DPP part -> y (pv_gemm accumulates the std part) ----
    float wsum = 0.f;
    #pragma unroll
    for (int s = 0; s < SMAX; ++s) if (s < sc) wsum += prow[wid][selI[s]];
    float yd = 0.f;
    #pragma unroll
    for (int s = 0; s < SMAX; ++s)
        if (s < sc) yd = fmaf(prow[wid][selI[s]], vh[selI[s] * HDIM + lane], yd);
    const float gp = gate_p[0];
    const float gate = 1.f / (1.f + expf(-gp));
    y[((size_t)n * SEQ + i) * HDIM + lane] = gate * yd / wsum;
    if (lane == 0) denomArr[n * SEQ + i] = denom;
}

// ---------------------------------------------------------------
// Kernel 4: y += (1-gate) * (P @ V)/denom  (causal j-chunk skip)
// ---------------------------------------------------------------
__global__ __launch_bounds__(256) void pv_gemm_kernel(
    const float* __restrict__ P, const float* __restrict__ v,
    const float* __restrict__ denomArr, const float* __restrict__ gate_p,
    float* __restrict__ y)
{
    __shared__ float Ps[32][68];   // [j][token]
    __shared__ float Vs[32][68];   // [j][d]
    const int tt = blockIdx.x;
    const int n  = blockIdx.y;
    const int t0 = tt * 64;
    const int tid = threadIdx.x;
    const float* Ph = P + (size_t)n * SEQ * SEQ;
    const float* vh = v + (size_t)n * SEQ * HDIM;
    const int tm = (tid >> 4) << 2;
    const int tn = (tid & 15) << 2;
    float acc[4][4] = {};
    const int jmax = t0 + 64;
    for (int j0 = 0; j0 < jmax; j0 += 32) {
        #pragma unroll
        for (int l = 0; l < 2; ++l) {
            int idx = tid + l * 256;
            int tok = idx >> 3, j4 = (idx & 7) << 2;
            float4 p4 = *(const float4*)(Ph + (t0 + tok) * SEQ + j0 + j4);
            Ps[j4 + 0][tok] = p4.x; Ps[j4 + 1][tok] = p4.y;
            Ps[j4 + 2][tok] = p4.z; Ps[j4 + 3][tok] = p4.w;
        }
        #pragma unroll
        for (int l = 0; l < 2; ++l) {
            int idx = tid + l * 256;
            int j = idx >> 4, d4 = (idx & 15) << 2;
            *(float4*)&Vs[j][d4] = *(const float4*)(vh + (j0 + j) * HDIM + d4);
        }
        __syncthreads();
        #pragma unroll
        for (int j = 0; j < 32; ++j) {
            float4 a4 = *(const float4*)&Ps[j][tm];
            float4 b4 = *(const float4*)&Vs[j][tn];
            float a[4] = {a4.x, a4.y, a4.z, a4.w};
            float b[4] = {b4.x, b4.y, b4.z, b4.w};
            #pragma unroll
            for (int u = 0; u < 4; ++u)
                #pragma unroll
                for (int w2 = 0; w2 < 4; ++w2)
                    acc[u][w2] = fmaf(a[u], b[w2], acc[u][w2]);
        }
        __syncthreads();
    }
    const float gp = gate_p[0];
    const float gate = 1.f / (1.f + expf(-gp));
    #pragma unroll
    for (int u = 0; u < 4; ++u) {
        int i = t0 + tm + u;
        float den = denomArr[n * SEQ + i];
        #pragma unroll
        for (int w2 = 0; w2 < 4; ++w2) {
            int d = tn + w2;
            size_t off = ((size_t)n * SEQ + i) * HDIM + d;
            y[off] += (1.f - gate) * acc[u][w2] / den;
        }
    }
}

// ---------------------------------------------------------------
// Kernel 5: out = reshape(y) @ w_proj + b_proj (gathered A)
// ---------------------------------------------------------------
__global__ __launch_bounds__(256) void proj_gemm_kernel(
    const float* __restrict__ y, const float* __restrict__ w,
    const float* __restrict__ bias, float* __restrict__ out)
{
    __shared__ float As[16][68];
    __shared__ float Bs[16][68];
    const int bm = blockIdx.y * 64;
    const int bn = blockIdx.x * 64;
    const int tid = threadIdx.x;
    const int tm = (tid >> 4) << 2;
    const int tn = (tid & 15) << 2;
    const int lm = tid >> 2;
    const int lkq = (tid & 3) << 2;
    const int lkk = tid >> 4;
    const int lnq = (tid & 15) << 2;
    float acc[4][4] = {};
    for (int k0 = 0; k0 < CDIM; k0 += 16) {
        int row = bm + lm;
        int col = k0 + lkq;
        int b_ = row >> 9, t = row & 511;
        int h = col >> 6, d = col & 63;
        float4 av = *(const float4*)(y + (((b_ * NHEAD + h) * SEQ) + t) * HDIM + d);
        float4 bv = *(const float4*)(w + (k0 + lkk) * CDIM + bn + lnq);
        As[lkq + 0][lm] = av.x;
        As[lkq + 1][lm] = av.y;
        As[lkq + 2][lm] = av.z;
        As[lkq + 3][lm] = av.w;
        *(float4*)&Bs[lkk][lnq] = bv;
        __syncthreads();
        #pragma unroll
        for (int kk = 0; kk < 16; ++kk) {
            float4 a4 = *(const float4*)&As[kk][tm];
            float4 b4 = *(const float4*)&Bs[kk][tn];
            float a[4] = {a4.x, a4.y, a4.z, a4.w};
            float b[4] = {b4.x, b4.y, b4.z, b4.w};
            #pragma unroll
            for (int u = 0; u < 4; ++u)
                #pragma unroll
                for (int w2 = 0; w2 < 4; ++w2)
                    acc[u][w2] = fmaf(a[u], b[w2], acc[u][w2]);
        }
        __syncthreads();
    }
    #pragma unroll
    for (int u = 0; u < 4; ++u) {
        int m = bm + tm + u;
        #pragma unroll
        for (int w2 = 0; w2 < 4; ++w2) {
            int cc = bn + tn + w2;
            out[m * CDIM + cc] = acc[u][w2] + bias[cc];
        }
    }
}

extern "C" void kernel_launch(void* const* d_in, const int* in_sizes, int n_in,
                              void* d_out, int out_size, void* d_ws, size_t ws_size,
                              hipStream_t stream)
{
    const float* x      = (const float*)d_in[0];
    const float* w_qkv  = (const float*)d_in[1];
    const float* b_qkv  = (const float*)d_in[2];
    const float* w_proj = (const float*)d_in[3];
    const float* b_proj = (const float*)d_in[4];
    const float* gate_p = (const float*)d_in[5];
    float* out = (float*)d_out;

    float* ws = (float*)d_ws;
    const size_t HS = (size_t)NBATCH * NHEAD * SEQ * HDIM;   // 786432
    const size_t SS = (size_t)NBATCH * NHEAD * SEQ * SEQ;    // 6291456
    float* q   = ws;
    float* k   = q + HS;
    float* v   = k + HS;
    float* y   = v + HS;
    float* S   = y + HS;                 // sim, becomes P in-place
    float* den = S + SS;
    float* KKT = den + 16384;            // 24*36*4096 floats, packed tiles

    qkv_gemm_kernel<<<dim3((3 * CDIM) / 64, (NBATCH * SEQ) / 64), 256, 0, stream>>>(
        x, w_qkv, b_qkv, q, k, v);
    sgemm_qk_kernel<<<dim3(36, NBATCH * NHEAD), 256, 0, stream>>>(q, k, S);
    kkt_gemm_kernel<<<dim3(36, NBATCH * NHEAD), 256, 0, stream>>>(k, KKT);
    dpp_kernel<<<dim3(SEQ / 4, NBATCH * NHEAD), 256, 0, stream>>>(
        v, S, KKT, gate_p, y, den);
    pv_gemm_kernel<<<dim3(SEQ / 64, NBATCH * NHEAD), 256, 0, stream>>>(
        S, v, den, gate_p, y);
    proj_gemm_kernel<<<dim3(CDIM / 64, (NBATCH * SEQ) / 64), 256, 0, stream>>>(
        y, w_proj, b_proj, out);
}

// Round 6
// 220.893 us; speedup vs baseline: 3.2150x; 1.1914x over previous
//
#include <hip/hip_runtime.h>
#include <math.h>

// Problem constants
constexpr int SEQ   = 512;
constexpr int HDIM  = 64;
constexpr int NHEAD = 12;
constexpr int NBATCH = 2;
constexpr int CDIM  = 768;
constexpr int TOPM  = 16;
constexpr int SMAX  = 8;
constexpr float NEGINF = -1e30f;

// ---------------------------------------------------------------
// Kernel 1: QKV = x @ w_qkv + b_qkv, scattered to q/k/v [24,512,64]
// 64x64 tile, BK=32 (half the barriers of BK=16), 4x4 micro.
// K-summation order identical to prior rounds (ascending k) ->
// bitwise-identical q/k/v.
// ---------------------------------------------------------------
__global__ __launch_bounds__(256) void qkv_gemm_kernel(
    const float* __restrict__ x, const float* __restrict__ w,
    const float* __restrict__ bias,
    float* __restrict__ q, float* __restrict__ k, float* __restrict__ v)
{
    __shared__ float As[32][68];
    __shared__ float Bs[32][68];
    const int bm = blockIdx.y * 64;
    const int bn = blockIdx.x * 64;
    const int tid = threadIdx.x;
    const int tm = (tid >> 4) << 2;
    const int tn = (tid & 15) << 2;
    // A staging: row = tid>>2 (64 rows), k-offset = (tid&3)*8, two float4
    const int alm = tid >> 2;
    const int alk = (tid & 3) << 3;
    // B staging: kk = tid>>3 (32 rows), n-offset = (tid&7)*8, two float4
    const int blk = tid >> 3;
    const int bln = (tid & 7) << 3;
    float acc[4][4] = {};
    for (int k0 = 0; k0 < CDIM; k0 += 32) {
        float4 a0 = *(const float4*)(x + (bm + alm) * CDIM + k0 + alk);
        float4 a1 = *(const float4*)(x + (bm + alm) * CDIM + k0 + alk + 4);
        float4 b0 = *(const float4*)(w + (k0 + blk) * (3 * CDIM) + bn + bln);
        float4 b1 = *(const float4*)(w + (k0 + blk) * (3 * CDIM) + bn + bln + 4);
        As[alk + 0][alm] = a0.x; As[alk + 1][alm] = a0.y;
        As[alk + 2][alm] = a0.z; As[alk + 3][alm] = a0.w;
        As[alk + 4][alm] = a1.x; As[alk + 5][alm] = a1.y;
        As[alk + 6][alm] = a1.z; As[alk + 7][alm] = a1.w;
        *(float4*)&Bs[blk][bln] = b0;
        *(float4*)&Bs[blk][bln + 4] = b1;
        __syncthreads();
        #pragma unroll
        for (int kk = 0; kk < 32; ++kk) {
            float4 a4 = *(const float4*)&As[kk][tm];
            float4 b4 = *(const float4*)&Bs[kk][tn];
            float a[4] = {a4.x, a4.y, a4.z, a4.w};
            float b[4] = {b4.x, b4.y, b4.z, b4.w};
            #pragma unroll
            for (int u = 0; u < 4; ++u)
                #pragma unroll
                for (int w2 = 0; w2 < 4; ++w2)
                    acc[u][w2] = fmaf(a[u], b[w2], acc[u][w2]);
        }
        __syncthreads();
    }
    #pragma unroll
    for (int u = 0; u < 4; ++u) {
        int m = bm + tm + u;
        int b_ = m >> 9, t = m & 511;
        #pragma unroll
        for (int w2 = 0; w2 < 4; ++w2) {
            int cc = bn + tn + w2;
            float val = acc[u][w2] + bias[cc];
            int part = cc / CDIM;
            int c2 = cc - part * CDIM;
            int h = c2 >> 6, d = c2 & 63;
            float* dst = (part == 0) ? q : ((part == 1) ? k : v);
            dst[(((b_ * NHEAD + h) * SEQ) + t) * HDIM + d] = val;
        }
    }
}

// ---------------------------------------------------------------
// Kernel 2: fused S = QK^T and KKT (lower-tri 64x64 tiles).
// Shares the K[jt] tile staging. S fp32 (same order as before ->
// identical bits); KKT fp64-accum, fp32 single-rounded store.
// ---------------------------------------------------------------
__global__ __launch_bounds__(256) void qkkt_kernel(
    const float* __restrict__ q, const float* __restrict__ k,
    float* __restrict__ S, float* __restrict__ KKT)
{
    __shared__ float Qs[64][68];   // [d][token_i]
    __shared__ float Ka[64][68];   // [d][token_i] keys (row tile)
    __shared__ float Kb[64][68];   // [d][token_j] keys (col tile)
    const int e = blockIdx.x;      // 0..35 lower-tri tile
    const int n = blockIdx.y;
    int it = 0, start = 0;
    while (start + it + 1 <= e) { start += it + 1; ++it; }
    const int jt = e - start;
    const int tid = threadIdx.x;
    const float* qh = q + (size_t)n * SEQ * HDIM;
    const float* kh = k + (size_t)n * SEQ * HDIM;

    #pragma unroll
    for (int l = 0; l < 4; ++l) {
        int idx = tid + l * 256;             // 0..1023
        int tok = idx >> 4, q4 = (idx & 15) << 2;
        float4 qv = *(const float4*)(qh + (it * 64 + tok) * HDIM + q4);
        Qs[q4 + 0][tok] = qv.x; Qs[q4 + 1][tok] = qv.y;
        Qs[q4 + 2][tok] = qv.z; Qs[q4 + 3][tok] = qv.w;
        float4 ka = *(const float4*)(kh + (it * 64 + tok) * HDIM + q4);
        Ka[q4 + 0][tok] = ka.x; Ka[q4 + 1][tok] = ka.y;
        Ka[q4 + 2][tok] = ka.z; Ka[q4 + 3][tok] = ka.w;
        float4 kb = *(const float4*)(kh + (jt * 64 + tok) * HDIM + q4);
        Kb[q4 + 0][tok] = kb.x; Kb[q4 + 1][tok] = kb.y;
        Kb[q4 + 2][tok] = kb.z; Kb[q4 + 3][tok] = kb.w;
    }
    __syncthreads();

    const int tm = (tid >> 4) << 2;
    const int tn = (tid & 15) << 2;
    float  sacc[4][4] = {};
    double gacc[4][4] = {};
    #pragma unroll 4
    for (int d = 0; d < 64; ++d) {
        float4 q4 = *(const float4*)&Qs[d][tm];
        float4 a4 = *(const float4*)&Ka[d][tm];
        float4 b4 = *(const float4*)&Kb[d][tn];
        float qa[4] = {q4.x, q4.y, q4.z, q4.w};
        float aa[4] = {a4.x, a4.y, a4.z, a4.w};
        float bb[4] = {b4.x, b4.y, b4.z, b4.w};
        #pragma unroll
        for (int u = 0; u < 4; ++u)
            #pragma unroll
            for (int w2 = 0; w2 < 4; ++w2) {
                sacc[u][w2] = fmaf(qa[u], bb[w2], sacc[u][w2]);
                gacc[u][w2] = fma((double)aa[u], (double)bb[w2], gacc[u][w2]);
            }
    }
    float* gdst = KKT + ((size_t)n * 36 + e) * 4096;
    #pragma unroll
    for (int u = 0; u < 4; ++u) {
        int i = it * 64 + tm + u;
        float4 o = {sacc[u][0], sacc[u][1], sacc[u][2], sacc[u][3]};
        *(float4*)(S + ((size_t)n * SEQ + i) * SEQ + jt * 64 + tn) = o;
        float4 g = {(float)gacc[u][0], (float)gacc[u][1],
                    (float)gacc[u][2], (float)gacc[u][3]};
        *(float4*)(gdst + (tm + u) * 64 + tn) = g;
    }
}

// hybrid log: exact exponent + hardware f32 log2 of mantissa.
// abs err ~1e-7 << ref's fp32-det/fp32-log noise (~4e-6).
__device__ inline double hybrid_log(double a)
{
    a = fmax(a, 1e-300);
    unsigned long long b = __double_as_longlong(a);
    int e2 = (int)((b >> 52) & 0x7FF) - 1022;
    double m = __longlong_as_double((b & 0x000FFFFFFFFFFFFFULL) |
                                    0x3FE0000000000000ULL);   // [0.5,1)
    return ((double)__log2f((float)m) + (double)e2) * 0.6931471805599453;
}

// ---------------------------------------------------------------
// Kernel 3: per-token DPP. One wave per token, 4 tokens per block.
// ---------------------------------------------------------------
__global__ __launch_bounds__(256) void dpp_kernel(
    const float* __restrict__ v, float* __restrict__ S,
    const float* __restrict__ KKT, const float* __restrict__ gate_p,
    float* __restrict__ y, float* __restrict__ denomArr)
{
    const int tid  = threadIdx.x;
    const int wid  = tid >> 6;
    const int lane = tid & 63;
    const int i = blockIdx.x * 4 + wid;
    const int n = blockIdx.y;
    const float* vh = v + (size_t)n * SEQ * HDIM;
    const float* KKTh = KKT + (size_t)n * 36 * 4096;
    float* Srow = S + ((size_t)n * SEQ + i) * SEQ;

    __shared__ float  prow[4][SEQ];
    __shared__ double gram[4][17][17];
    __shared__ int    eidx[4][17];

    // ---- load sim row (masked) ----
    float sim8[8];
    #pragma unroll
    for (int m = 0; m < 8; ++m) {
        int j = lane + (m << 6);
        sim8[m] = (j <= i) ? Srow[j] : NEGINF;
    }

    // ---- top-16 via packed sortable-u64 key (stable ties = lowest idx) ----
    {
        float vals[8];
        #pragma unroll
        for (int m = 0; m < 8; ++m) vals[m] = sim8[m];
        if (lane == 0) eidx[wid][0] = i;
        #pragma unroll
        for (int s = 0; s < TOPM; ++s) {
            float bv = vals[0]; int bi = lane;
            #pragma unroll
            for (int m = 1; m < 8; ++m)
                if (vals[m] > bv) { bv = vals[m]; bi = lane + (m << 6); }
            unsigned u = __float_as_uint(bv);
            u ^= (u & 0x80000000u) ? 0xFFFFFFFFu : 0x80000000u;
            unsigned long long key =
                ((unsigned long long)u << 9) | (unsigned)(511 - bi);
            #pragma unroll
            for (int off = 32; off; off >>= 1) {
                unsigned long long ok = __shfl_xor(key, off);
                if (ok > key) key = ok;
            }
            int ri = 511 - (int)(key & 511ull);
            if (lane == 0) eidx[wid][1 + s] = ri;
            if ((ri & 63) == lane) {
                int om = ri >> 6;
                #pragma unroll
                for (int m = 0; m < 8; ++m) if (m == om) vals[m] = -2e30f;
            }
        }
    }

    // ---- softmax stats; write numerators to LDS + global (P over S) ----
    const float scale = 0.125f;
    float lm = -3e38f;
    #pragma unroll
    for (int m = 0; m < 8; ++m) lm = fmaxf(lm, sim8[m]);
    #pragma unroll
    for (int off = 32; off; off >>= 1) lm = fmaxf(lm, __shfl_xor(lm, off));
    const float mx = lm * scale;
    float sum = 0.f;
    #pragma unroll
    for (int m = 0; m < 8; ++m) {
        float p = expf(sim8[m] * scale - mx);   // 0 for masked entries
        int j = lane + (m << 6);
        prow[wid][j] = p;
        Srow[j] = p;
        sum += p;
    }
    #pragma unroll
    for (int off = 32; off; off >>= 1) sum += __shfl_xor(sum, off);
    const float denom = sum;
    __syncthreads();

    // ---- 17x17 Gram: gather from precomputed KKT ----
    for (int e = lane; e < 153; e += 64) {
        int a = 0, st = 0;
        while (st + a + 1 <= e) { st += a + 1; ++a; }
        int b = e - st;
        int ra = eidx[wid][a], rb = eidx[wid][b];
        int row = ra > rb ? ra : rb;
        int col = ra > rb ? rb : ra;
        int itt = row >> 6, jtt = col >> 6;
        int p = ((itt * (itt + 1)) >> 1) + jtt;
        double s = (double)KKTh[((size_t)p * 64 + (row & 63)) * 64 + (col & 63)];
        gram[wid][a][b] = s;
        gram[wid][b][a] = s;
    }
    __syncthreads();

    // ---- greedy DPP via incremental Cholesky ----
    // argmax runs on arg = det*dc + eps (monotone <=> score within an
    // iteration); arg<=0 maps to +huge (= ref's NaN-wins-argmax). The
    // single log per iteration uses hybrid_log (hw f32 log2).
    int selI[SMAX];
    int sc = 1;
    {
        const int c = lane;
        const bool isCand = (c < TOPM);
        const int nvalid = (i + 1 < TOPM) ? (i + 1) : TOPM;
        bool active = isCand && (c < nvalid) && (eidx[wid][1 + c] != i);
        double zc[7];
        #pragma unroll
        for (int t = 0; t < 7; ++t) zc[t] = 0.0;
        double det = gram[wid][0][0];
        double cur = hybrid_log(det + 1e-6);
        double L00 = sqrt(det > 0.0 ? det : 1e-30);
        double dcv = 0.0;
        if (isCand) {
            zc[0] = gram[wid][1 + c][0] / L00;
            dcv = gram[wid][1 + c][1 + c] - zc[0] * zc[0];
        }
        #pragma unroll
        for (int t = 0; t < SMAX; ++t) selI[t] = i;

        for (int it = 0; it < SMAX - 1; ++it) {
            double argc = det * dcv + 1e-6;
            // candidate ranking key (monotone in score; arg<=0 == NaN wins)
            double key = active ? (argc > 0.0 ? argc : 1e300) : -1.0;
            int rc = c;
            #pragma unroll
            for (int off = 1; off <= 8; off <<= 1) {   // reduce among 16 cands
                double ov = __shfl_xor(key, off);
                int    oc = __shfl_xor(rc, off);
                if (ov > key || (ov == key && oc < rc)) { key = ov; rc = oc; }
            }
            rc = __shfl(rc, 0);                        // broadcast winner
            bool any = (__any(active ? 1 : 0) != 0);
            double dbest = __shfl(dcv, rc);
            double argb = det * dbest + 1e-6;
            bool   pos  = argb > 0.0;
            double score = hybrid_log(pos ? argb : 1.0) / (double)(sc + 1);
            bool take = any && ((pos && score > cur) || (sc < 4));
            if (!take) break;

            double Lss = sqrt(dbest > 1e-30 ? dbest : 1e-30);
            double zb[7];
            #pragma unroll
            for (int t = 0; t < 7; ++t) zb[t] = __shfl(zc[t], rc);
            if (isCand) {
                double crossn = gram[wid][1 + c][1 + rc];
                double s2 = 0.0;
                #pragma unroll
                for (int t = 0; t < 7; ++t) if (t < sc) s2 += zc[t] * zb[t];
                double znew = (crossn - s2) / Lss;
                #pragma unroll
                for (int t = 0; t < 7; ++t) if (t == sc) zc[t] = znew;
                dcv -= znew * znew;
            }
            det = det * dbest;
            cur = pos ? score : __builtin_nan("");     // NaN: future cmp false
            if (c == rc) active = false;
            int newIdx = eidx[wid][1 + rc];
            #pragma unroll
            for (int t = 0; t < SMAX; ++t) if (t == sc) selI[t] = newIdx;
            ++sc;
        }
    }

    // ---- gated DPP part -> y (pv_gemm accumulates the std part) ----
    float wsum = 0.f;
    #pragma unroll
    for (int s = 0; s < SMAX; ++s) if (s < sc) wsum += prow[wid][selI[s]];
    float yd = 0.f;
    #pragma unroll
    for (int s = 0; s < SMAX; ++s)
        if (s < sc) yd = fmaf(prow[wid][selI[s]], vh[selI[s] * HDIM + lane], yd);
    const float gp = gate_p[0];
    const float gate = 1.f / (1.f + expf(-gp));
    y[((size_t)n * SEQ + i) * HDIM + lane] = gate * yd / wsum;
    if (lane == 0) denomArr[n * SEQ + i] = denom;
}

// ---------------------------------------------------------------
// Kernel 4: y += (1-gate) * (P @ V)/denom  (causal j-chunk skip)
// ---------------------------------------------------------------
__global__ __launch_bounds__(256) void pv_gemm_kernel(
    const float* __restrict__ P, const float* __restrict__ v,
    const float* __restrict__ denomArr, const float* __restrict__ gate_p,
    float* __restrict__ y)
{
    __shared__ float Ps[32][68];   // [j][token]
    __shared__ float Vs[32][68];   // [j][d]
    const int tt = blockIdx.x;
    const int n  = blockIdx.y;
    const int t0 = tt * 64;
    const int tid = threadIdx.x;
    const float* Ph = P + (size_t)n * SEQ * SEQ;
    const float* vh = v + (size_t)n * SEQ * HDIM;
    const int tm = (tid >> 4) << 2;
    const int tn = (tid & 15) << 2;
    float acc[4][4] = {};
    const int jmax = t0 + 64;
    for (int j0 = 0; j0 < jmax; j0 += 32) {
        #pragma unroll
        for (int l = 0; l < 2; ++l) {
            int idx = tid + l * 256;
            int tok = idx >> 3, j4 = (idx & 7) << 2;
            float4 p4 = *(const float4*)(Ph + (t0 + tok) * SEQ + j0 + j4);
            Ps[j4 + 0][tok] = p4.x; Ps[j4 + 1][tok] = p4.y;
            Ps[j4 + 2][tok] = p4.z; Ps[j4 + 3][tok] = p4.w;
        }
        #pragma unroll
        for (int l = 0; l < 2; ++l) {
            int idx = tid + l * 256;
            int j = idx >> 4, d4 = (idx & 15) << 2;
            *(float4*)&Vs[j][d4] = *(const float4*)(vh + (j0 + j) * HDIM + d4);
        }
        __syncthreads();
        #pragma unroll
        for (int j = 0; j < 32; ++j) {
            float4 a4 = *(const float4*)&Ps[j][tm];
            float4 b4 = *(const float4*)&Vs[j][tn];
            float a[4] = {a4.x, a4.y, a4.z, a4.w};
            float b[4] = {b4.x, b4.y, b4.z, b4.w};
            #pragma unroll
            for (int u = 0; u < 4; ++u)
                #pragma unroll
                for (int w2 = 0; w2 < 4; ++w2)
                    acc[u][w2] = fmaf(a[u], b[w2], acc[u][w2]);
        }
        __syncthreads();
    }
    const float gp = gate_p[0];
    const float gate = 1.f / (1.f + expf(-gp));
    #pragma unroll
    for (int u = 0; u < 4; ++u) {
        int i = t0 + tm + u;
        float den = denomArr[n * SEQ + i];
        #pragma unroll
        for (int w2 = 0; w2 < 4; ++w2) {
            int d = tn + w2;
            size_t off = ((size_t)n * SEQ + i) * HDIM + d;
            y[off] += (1.f - gate) * acc[u][w2] / den;
        }
    }
}

// ---------------------------------------------------------------
// Kernel 5: out = reshape(y) @ w_proj + b_proj (gathered A), BK=32
// ---------------------------------------------------------------
__global__ __launch_bounds__(256) void proj_gemm_kernel(
    const float* __restrict__ y, const float* __restrict__ w,
    const float* __restrict__ bias, float* __restrict__ out)
{
    __shared__ float As[32][68];
    __shared__ float Bs[32][68];
    const int bm = blockIdx.y * 64;
    const int bn = blockIdx.x * 64;
    const int tid = threadIdx.x;
    const int tm = (tid >> 4) << 2;
    const int tn = (tid & 15) << 2;
    const int alm = tid >> 2;
    const int alk = (tid & 3) << 3;
    const int blk = tid >> 3;
    const int bln = (tid & 7) << 3;
    float acc[4][4] = {};
    for (int k0 = 0; k0 < CDIM; k0 += 32) {
        int row = bm + alm;
        int b_ = row >> 9, t = row & 511;
        int col0 = k0 + alk;
        int h0 = col0 >> 6, d0 = col0 & 63;
        float4 a0 = *(const float4*)(y + (((b_ * NHEAD + h0) * SEQ) + t) * HDIM + d0);
        int col1 = col0 + 4;
        int h1 = col1 >> 6, d1 = col1 & 63;
        float4 a1 = *(const float4*)(y + (((b_ * NHEAD + h1) * SEQ) + t) * HDIM + d1);
        float4 b0 = *(const float4*)(w + (k0 + blk) * CDIM + bn + bln);
        float4 b1 = *(const float4*)(w + (k0 + blk) * CDIM + bn + bln + 4);
        As[alk + 0][alm] = a0.x; As[alk + 1][alm] = a0.y;
        As[alk + 2][alm] = a0.z; As[alk + 3][alm] = a0.w;
        As[alk + 4][alm] = a1.x; As[alk + 5][alm] = a1.y;
        As[alk + 6][alm] = a1.z; As[alk + 7][alm] = a1.w;
        *(float4*)&Bs[blk][bln] = b0;
        *(float4*)&Bs[blk][bln + 4] = b1;
        __syncthreads();
        #pragma unroll
        for (int kk = 0; kk < 32; ++kk) {
            float4 a4 = *(const float4*)&As[kk][tm];
            float4 b4 = *(const float4*)&Bs[kk][tn];
            float a[4] = {a4.x, a4.y, a4.z, a4.w};
            float b[4] = {b4.x, b4.y, b4.z, b4.w};
            #pragma unroll
            for (int u = 0; u < 4; ++u)
                #pragma unroll
                for (int w2 = 0; w2 < 4; ++w2)
                    acc[u][w2] = fmaf(a[u], b[w2], acc[u][w2]);
        }
        __syncthreads();
    }
    #pragma unroll
    for (int u = 0; u < 4; ++u) {
        int m = bm + tm + u;
        #pragma unroll
        for (int w2 = 0; w2 < 4; ++w2) {
            int cc = bn + tn + w2;
            out[m * CDIM + cc] = acc[u][w2] + bias[cc];
        }
    }
}

extern "C" void kernel_launch(void* const* d_in, const int* in_sizes, int n_in,
                              void* d_out, int out_size, void* d_ws, size_t ws_size,
                              hipStream_t stream)
{
    const float* x      = (const float*)d_in[0];
    const float* w_qkv  = (const float*)d_in[1];
    const float* b_qkv  = (const float*)d_in[2];
    const float* w_proj = (const float*)d_in[3];
    const float* b_proj = (const float*)d_in[4];
    const float* gate_p = (const float*)d_in[5];
    float* out = (float*)d_out;

    float* ws = (float*)d_ws;
    const size_t HS = (size_t)NBATCH * NHEAD * SEQ * HDIM;   // 786432
    const size_t SS = (size_t)NBATCH * NHEAD * SEQ * SEQ;    // 6291456
    float* q   = ws;
    float* k   = q + HS;
    float* v   = k + HS;
    float* y   = v + HS;
    float* S   = y + HS;                 // sim, becomes P in-place
    float* den = S + SS;
    float* KKT = den + 16384;            // 24*36*4096 floats, packed tiles

    qkv_gemm_kernel<<<dim3((3 * CDIM) / 64, (NBATCH * SEQ) / 64), 256, 0, stream>>>(
        x, w_qkv, b_qkv, q, k, v);
    qkkt_kernel<<<dim3(36, NBATCH * NHEAD), 256, 0, stream>>>(q, k, S, KKT);
    dpp_kernel<<<dim3(SEQ / 4, NBATCH * NHEAD), 256, 0, stream>>>(
        v, S, KKT, gate_p, y, den);
    pv_gemm_kernel<<<dim3(SEQ / 64, NBATCH * NHEAD), 256, 0, stream>>>(
        S, v, den, gate_p, y);
    proj_gemm_kernel<<<dim3(CDIM / 64, (NBATCH * SEQ) / 64), 256, 0, stream>>>(
        y, w_proj, b_proj, out);
}